// Round 11
// baseline (3439.642 us; speedup 1.0000x reference)
//
#include <hip/hip_runtime.h>
#include <math.h>

#define EPSV 1e-5f

typedef _Float16 v2h __attribute__((ext_vector_type(2)));

__device__ __forceinline__ float sigf(float x){ return 1.0f/(1.0f+__expf(-x)); }
__device__ __forceinline__ float tanhf_(float x){
  float c = fminf(fmaxf(x,-10.f),10.f);
  float e = __expf(2.0f*c);
  return (e-1.0f)/(e+1.0f);
}

// LDS-only barrier: drains lgkmcnt but NOT vmcnt.
__device__ __forceinline__ void ldsbar(){
  asm volatile("s_waitcnt lgkmcnt(0)\n\ts_barrier" ::: "memory");
}

__device__ __forceinline__ float dot2u(unsigned int a, unsigned int b, float c){
#if __has_builtin(__builtin_amdgcn_fdot2)
  v2h av = __builtin_bit_cast(v2h, a);
  v2h bv = __builtin_bit_cast(v2h, b);
  return __builtin_amdgcn_fdot2(av, bv, c, false);
#else
  v2h av = __builtin_bit_cast(v2h, a);
  v2h bv = __builtin_bit_cast(v2h, b);
  return c + (float)av.x*(float)bv.x + (float)av.y*(float)bv.y;
#endif
}

// ---------------- LN over channel dim -> channel-last seq ----------------
__global__ void k_ln_chan(const float* __restrict__ src, float* __restrict__ dst,
                          const float* __restrict__ g, const float* __restrict__ bb, int mode){
  int i = blockIdx.x*blockDim.x + threadIdx.x;
  const int total = 2*250*65;
  if (i >= total) return;
  int q = i % 65; int t = (i/65) % 250; int b = i/(65*250);
  const float* p = src + (size_t)b*48*250*65 + (size_t)t*65 + q;
  float s=0.f, ss=0.f;
  for (int c=0;c<48;c++){ float v = p[(size_t)c*250*65]; s+=v; ss+=v*v; }
  float mu = s*(1.0f/48.0f);
  float var = ss*(1.0f/48.0f) - mu*mu;
  float rs = rsqrtf(fmaxf(var, EPSV));
  float* d = (mode==0) ? dst + ((size_t)(b*250+t)*65 + q)*48
                       : dst + ((size_t)(b*65+q)*250 + t)*48;
  for (int c=0;c<48;c++){ float v = p[(size_t)c*250*65]; d[c] = (v-mu)*rs*g[c] + bb[c]; }
}

// ---------------- fused qkv + MHA: block per (n,h), qkv computed in-block ----------------
__global__ __launch_bounds__(256) void k_mha2(
    const float* __restrict__ seq, const float* __restrict__ inw,
    const float* __restrict__ inb, float* __restrict__ att, int N, int L){
  __shared__ float shq[250*12];
  __shared__ float shk[250*12];
  __shared__ float shv[250*12];
  int n = blockIdx.x, h = blockIdx.y;
  for (int i = threadIdx.x; i < L*36; i += 256){
    int l = i/36, jj = i - (i/36)*36;
    int sect = jj/12, d = jj - sect*12;
    int j = sect*48 + h*12 + d;
    const float* srow = seq + ((size_t)n*L + l)*48;
    const float* wrow = inw + j*48;
    float acc = inb[j];
    for (int c=0;c<48;c++) acc += srow[c]*wrow[c];
    float* dst = (sect==0)?shq:(sect==1)?shk:shv;
    dst[l*12+d] = acc;
  }
  __syncthreads();
  const float scale = 0.28867513459481287f;
  for (int r = threadIdx.x; r < L; r += 256){
    const float4* q4 = (const float4*)(shq + r*12);
    float4 q0 = q4[0], q1 = q4[1], q2 = q4[2];
    float m = -1e30f, den = 0.0f;
    float4 o0 = make_float4(0,0,0,0), o1 = make_float4(0,0,0,0), o2 = make_float4(0,0,0,0);
    for (int j=0; j<L; j++){
      const float4* k4 = (const float4*)(shk + j*12);
      float4 k0 = k4[0], k1 = k4[1], k2 = k4[2];
      float s = q0.x*k0.x + q0.y*k0.y + q0.z*k0.z + q0.w*k0.w
              + q1.x*k1.x + q1.y*k1.y + q1.z*k1.z + q1.w*k1.w
              + q2.x*k2.x + q2.y*k2.y + q2.z*k2.z + q2.w*k2.w;
      s *= scale;
      if (s > m){
        float corr = __expf(m - s);
        den *= corr;
        o0.x*=corr; o0.y*=corr; o0.z*=corr; o0.w*=corr;
        o1.x*=corr; o1.y*=corr; o1.z*=corr; o1.w*=corr;
        o2.x*=corr; o2.y*=corr; o2.z*=corr; o2.w*=corr;
        m = s;
      }
      float e = __expf(s - m);
      den += e;
      const float4* v4 = (const float4*)(shv + j*12);
      float4 v0 = v4[0], v1 = v4[1], v2 = v4[2];
      o0.x += e*v0.x; o0.y += e*v0.y; o0.z += e*v0.z; o0.w += e*v0.w;
      o1.x += e*v1.x; o1.y += e*v1.y; o1.z += e*v1.z; o1.w += e*v1.w;
      o2.x += e*v2.x; o2.y += e*v2.y; o2.z += e*v2.z; o2.w += e*v2.w;
    }
    float inv = 1.0f/den;
    float* outp = att + ((size_t)n*L + r)*48 + h*12;
    outp[0]=o0.x*inv; outp[1]=o0.y*inv; outp[2]=o0.z*inv; outp[3]=o0.w*inv;
    outp[4]=o1.x*inv; outp[5]=o1.y*inv; outp[6]=o1.z*inv; outp[7]=o1.w*inv;
    outp[8]=o2.x*inv; outp[9]=o2.y*inv; outp[10]=o2.z*inv; outp[11]=o2.w*inv;
  }
}

// ---------------- out proj + residual ----------------
__global__ void k_projres(const float* __restrict__ att, const float* __restrict__ seq,
                          const float* __restrict__ w, const float* __restrict__ bias,
                          float* __restrict__ dst, int NL){
  int i = blockIdx.x*blockDim.x + threadIdx.x;
  if (i >= NL*48) return;
  int o = i % 48; int nl = i/48;
  const float* ar = att + (size_t)nl*48;
  const float* wr = w + o*48;
  float acc = bias[o] + seq[i];
  for (int c=0;c<48;c++) acc += ar[c]*wr[c];
  dst[i] = acc;
}

// ---------------- torch_ln over last dim (48), in place ----------------
__global__ void k_rowln(float* __restrict__ buf, const float* __restrict__ g,
                        const float* __restrict__ bb, int NL){
  int nl = blockIdx.x*blockDim.x + threadIdx.x;
  if (nl >= NL) return;
  float* p = buf + (size_t)nl*48;
  float s=0.f, ss=0.f;
  for (int c=0;c<48;c++){ float v=p[c]; s+=v; ss+=v*v; }
  float mu = s*(1.0f/48.0f);
  float var = ss*(1.0f/48.0f) - mu*mu;
  float rs = rsqrtf(var + EPSV);
  for (int c=0;c<48;c++) p[c] = (p[c]-mu)*rs*g[c] + bb[c];
}

// ---------------- fused weight prep: 8x lstm wpack + 2x convT f16-pack ----------------
__global__ void k_prep(const float* __restrict__ s0, const float* __restrict__ s1,
                       const float* __restrict__ s2, const float* __restrict__ s3,
                       const float* __restrict__ s4, const float* __restrict__ s5,
                       const float* __restrict__ s6, const float* __restrict__ s7,
                       const float* __restrict__ c0, const float* __restrict__ c1,
                       unsigned int* __restrict__ wpk, unsigned int* __restrict__ wtp){
  int i = blockIdx.x*blockDim.x + threadIdx.x;
  if (i < 589824){
    int seg = i/73728, off = i - seg*73728;
    const float* w = (seg==0)?s0:(seg==1)?s1:(seg==2)?s2:(seg==3)?s3:(seg==4)?s4:(seg==5)?s5:(seg==6)?s6:s7;
    int g = off % 768, d2 = off / 768;
    v2h v; v.x = (_Float16)w[g*192 + 2*d2]; v.y = (_Float16)w[g*192 + 2*d2 + 1];
    wpk[(size_t)seg*73728 + (size_t)d2*768 + g] = __builtin_bit_cast(unsigned int, v);
  } else if (i < 589824 + 2*36864){
    int j = i - 589824;
    int seg = j/36864, off = j - seg*36864;
    const float* w = seg ? c1 : c0;
    int c = off % 48; int ii2 = (off/48) % 192; int k = off/(48*192);
    v2h v;
    v.x = (_Float16)w[(2*ii2)*192 + c*4 + k];
    v.y = (_Float16)w[(2*ii2+1)*192 + c*4 + k];
    wtp[(size_t)seg*36864 + off] = __builtin_bit_cast(unsigned int, v);
  }
}

// ---------------- pre-gates GEMM: pre[n][l][g] = u.wi^T + bi + bh (f16 out) ----------------
__global__ __launch_bounds__(256) void k_pregates(
    const float* __restrict__ seq2, const unsigned int* __restrict__ wi,
    const float* __restrict__ bi, const float* __restrict__ bh,
    _Float16* __restrict__ pre, int L2, int SL){
  __shared__ unsigned int ut[96*16];
  int n = blockIdx.y;
  int l0 = blockIdx.x*16;
  int t = threadIdx.x;
  for (int idx=t; idx<1536; idx+=256){
    int l = idx & 15, d2 = idx >> 4;
    int li = l0 + l;
    int c = d2 >> 1, k0 = (d2 & 1)*2;
    float u0=0.f, u1=0.f;
    if (li < L2){
      const float* p = seq2 + ((size_t)n*SL + li)*48;
      u0 = p[k0*48 + c];
      u1 = p[(k0+1)*48 + c];
    }
    v2h v; v.x=(_Float16)u0; v.y=(_Float16)u1;
    ut[d2*16 + l] = __builtin_bit_cast(unsigned int, v);
  }
  __syncthreads();
  float acc[3][16];
  float b0 = bi[t] + bh[t];
  float b1 = bi[t+256] + bh[t+256];
  float b2 = bi[t+512] + bh[t+512];
  #pragma unroll
  for (int l=0;l<16;l++){ acc[0][l]=b0; acc[1][l]=b1; acc[2][l]=b2; }
  #pragma unroll 4
  for (int d2=0; d2<96; d2++){
    unsigned int w0 = wi[(size_t)d2*768 + t];
    unsigned int w1 = wi[(size_t)d2*768 + t + 256];
    unsigned int w2 = wi[(size_t)d2*768 + t + 512];
    const uint4* u4 = (const uint4*)(ut + d2*16);
    #pragma unroll
    for (int l4=0; l4<4; l4++){
      uint4 uu = u4[l4];
      acc[0][l4*4+0] = dot2u(uu.x, w0, acc[0][l4*4+0]);
      acc[0][l4*4+1] = dot2u(uu.y, w0, acc[0][l4*4+1]);
      acc[0][l4*4+2] = dot2u(uu.z, w0, acc[0][l4*4+2]);
      acc[0][l4*4+3] = dot2u(uu.w, w0, acc[0][l4*4+3]);
      acc[1][l4*4+0] = dot2u(uu.x, w1, acc[1][l4*4+0]);
      acc[1][l4*4+1] = dot2u(uu.y, w1, acc[1][l4*4+1]);
      acc[1][l4*4+2] = dot2u(uu.z, w1, acc[1][l4*4+2]);
      acc[1][l4*4+3] = dot2u(uu.w, w1, acc[1][l4*4+3]);
      acc[2][l4*4+0] = dot2u(uu.x, w2, acc[2][l4*4+0]);
      acc[2][l4*4+1] = dot2u(uu.y, w2, acc[2][l4*4+1]);
      acc[2][l4*4+2] = dot2u(uu.z, w2, acc[2][l4*4+2]);
      acc[2][l4*4+3] = dot2u(uu.w, w2, acc[2][l4*4+3]);
    }
  }
  #pragma unroll
  for (int l=0;l<16;l++){
    int li = l0 + l;
    if (li < L2){
      _Float16* pr = pre + ((size_t)n*L2 + li)*768;
      pr[t]       = (_Float16)acc[0][l];
      pr[t+256]   = (_Float16)acc[1][l];
      pr[t+512]   = (_Float16)acc[2][l];
    }
  }
}

// ---------------- biLSTM scan v11: half weights LDS-resident, half L2-streamed ----------
// 512 thr: hf = t>>8 (0: d2 0..47 from LDS wshT[row][d2], 1: d2 48..95 streamed from L2).
// Halves L2 weight traffic per step (the measured roofline of lstm6).
template<int G>
__global__ __launch_bounds__(512,1) void k_lstm11(
    const _Float16* __restrict__ pre, unsigned int* __restrict__ rT2,
    const unsigned int* __restrict__ wh_f, const unsigned int* __restrict__ wh_b,
    int N, int L2){
  __shared__ unsigned int wshT[48*768];   // [row][d2], d2 in [0,48)  (147456 B)
  __shared__ unsigned int hh2[96*G];      // [d2][s] packed h pairs
  __shared__ float gpart[2*G*768];        // [hf][s][row]
  _Float16* hh2h = (_Float16*)hh2;
  int t = threadIdx.x;
  int hf = t >> 8, tt = t & 255;
  int dir = blockIdx.y;
  int n0 = blockIdx.x*G;
  const unsigned int* wh = dir ? wh_b : wh_f;

  // preload LDS half (coalesced global read, scattered LDS write)
  for (int idx=t; idx<48*768; idx+=512){
    int d2 = idx/768, row = idx - d2*768;
    wshT[row*48 + d2] = wh[idx];
  }
  for (int idx=t; idx<96*G; idx+=512) hh2[idx]=0u;

  const _Float16* prd = pre + (size_t)dir*(size_t)N*L2*768;
  float cst = 0.f;
  int as = t/192, aj = t - as*192;
  bool actv = (t < 192*G);
  const unsigned short* pbase = (const unsigned short*)prd;
  if (actv) pbase = (const unsigned short*)(prd + ((size_t)(n0+as)*L2)*768) + aj;
  __syncthreads();

  unsigned short c0=0,c1=0,c2=0,c3=0;
  {
    int l0 = dir ? (L2-1) : 0;
    if (actv){
      const unsigned short* pp = pbase + (size_t)l0*768;
      c0 = pp[0]; c1 = pp[192]; c2 = pp[384]; c3 = pp[576];
    }
  }

  const unsigned int* wstr = wh + 48*768 + tt;   // streamed half base (row tt)

  for (int step=0; step<L2; step++){
    int l = dir ? (L2-1-step) : step;
    int stepn = (step+1 < L2) ? (step+1) : step;
    int ln = dir ? (L2-1-stepn) : stepn;
    unsigned short pn0=0,pn1=0,pn2=0,pn3=0;
    if (actv){
      const unsigned short* pp = pbase + (size_t)ln*768;
      pn0 = pp[0]; pn1 = pp[192]; pn2 = pp[384]; pn3 = pp[576];
    }

    float acc0[G], acc1[G], acc2[G];
    #pragma unroll
    for (int s=0;s<G;s++){ acc0[s]=0.f; acc1[s]=0.f; acc2[s]=0.f; }

    if (hf==0){
      const uint4* w0p = (const uint4*)(wshT + (size_t)tt*48);
      const uint4* w1p = (const uint4*)(wshT + (size_t)(tt+256)*48);
      const uint4* w2p = (const uint4*)(wshT + (size_t)(tt+512)*48);
      #pragma unroll 4
      for (int blk=0; blk<12; blk++){
        unsigned int hw[4][G];
        if (G==1){
          uint4 hv = ((const uint4*)hh2)[blk];
          hw[0][0]=hv.x; hw[1][0]=hv.y; hw[2][0]=hv.z; hw[3][0]=hv.w;
        } else {
          uint4 ha = ((const uint4*)hh2)[blk*2];
          uint4 hb = ((const uint4*)hh2)[blk*2+1];
          hw[0][0]=ha.x; hw[0][1]=ha.y; hw[1][0]=ha.z; hw[1][1]=ha.w;
          hw[2][0]=hb.x; hw[2][1]=hb.y; hw[3][0]=hb.z; hw[3][1]=hb.w;
        }
        uint4 w0 = w0p[blk], w1 = w1p[blk], w2 = w2p[blk];
        const unsigned int* w0a = (const unsigned int*)&w0;
        const unsigned int* w1a = (const unsigned int*)&w1;
        const unsigned int* w2a = (const unsigned int*)&w2;
        #pragma unroll
        for (int j=0;j<4;j++){
          #pragma unroll
          for (int s=0;s<G;s++){
            acc0[s] = dot2u(hw[j][s], w0a[j], acc0[s]);
            acc1[s] = dot2u(hw[j][s], w1a[j], acc1[s]);
            acc2[s] = dot2u(hw[j][s], w2a[j], acc2[s]);
          }
        }
      }
    } else {
      #pragma unroll 8
      for (int i=0;i<48;i++){
        unsigned int h2v[G];
        if (G==1){ h2v[0] = hh2[48+i]; }
        else {
          uint2 hv = *(const uint2*)&hh2[(48+i)*2];
          h2v[0]=hv.x; h2v[1]=hv.y;
        }
        unsigned int w0 = wstr[(size_t)i*768];
        unsigned int w1 = wstr[(size_t)i*768 + 256];
        unsigned int w2 = wstr[(size_t)i*768 + 512];
        #pragma unroll
        for (int s=0;s<G;s++){
          acc0[s] = dot2u(h2v[s], w0, acc0[s]);
          acc1[s] = dot2u(h2v[s], w1, acc1[s]);
          acc2[s] = dot2u(h2v[s], w2, acc2[s]);
        }
      }
    }
    #pragma unroll
    for (int s=0;s<G;s++){
      gpart[(hf*G+s)*768 + tt]       = acc0[s];
      gpart[(hf*G+s)*768 + tt + 256] = acc1[s];
      gpart[(hf*G+s)*768 + tt + 512] = acc2[s];
    }
    ldsbar();

    if (actv){
      float gi = (float)__builtin_bit_cast(_Float16, c0);
      float gf = (float)__builtin_bit_cast(_Float16, c1);
      float gg = (float)__builtin_bit_cast(_Float16, c2);
      float go = (float)__builtin_bit_cast(_Float16, c3);
      #pragma unroll
      for (int hh=0; hh<2; hh++){
        const float* gp = gpart + (hh*G+as)*768;
        gi += gp[aj]; gf += gp[aj+192]; gg += gp[aj+384]; go += gp[aj+576];
      }
      float ig = sigf(gi), fg = sigf(gf), g2 = tanhf_(gg), og = sigf(go);
      cst = fg*cst + ig*g2;
      float hn = og*tanhf_(cst);
      hh2h[((aj>>1)*G + as)*2 + (aj&1)] = (_Float16)hn;
    }
    ldsbar();

    if (t < 96*G){
      int s = t/96, ii2 = t - s*96;
      unsigned int v = hh2[ii2*G + s];
      rT2[((size_t)(n0+s)*192 + dir*96 + ii2)*L2 + l] = v;
    }
    c0 = pn0; c1 = pn1; c2 = pn2; c3 = pn3;
  }
}

// ---------------- conv_transpose1d v4: scalar (SMEM) weights, coalesced rT2 reads -------
__global__ __launch_bounds__(256) void k_convt4(
    const unsigned int* __restrict__ rT2, const unsigned int* __restrict__ wtp,
    const float* __restrict__ bias, const float* __restrict__ resid,
    float* __restrict__ dst, int L2, int OL, int mode){
  int n = blockIdx.y;
  int pos = blockIdx.x*64 + (threadIdx.x & 63);
  int cq = __builtin_amdgcn_readfirstlane((int)(threadIdx.x >> 6));
  float acc[12];
  #pragma unroll
  for (int c=0;c<12;c++) acc[c]=0.f;
  const unsigned int* rbase = rT2 + (size_t)n*192*L2;
  for (int k=0;k<4;k++){
    int l = pos - k;
    bool v = (l>=0) && (l<L2);
    int lc = v ? l : 0;
    const unsigned int* wk = wtp + (size_t)k*192*48 + cq*12;
    #pragma unroll 4
    for (int ii2=0; ii2<192; ii2++){
      unsigned int rp = v ? rbase[(size_t)ii2*L2 + lc] : 0u;
      const unsigned int* wrow = wk + ii2*48;
      #pragma unroll
      for (int c=0;c<12;c++) acc[c] = dot2u(rp, wrow[c], acc[c]);
    }
  }
  if (pos < OL){
    for (int c12=0;c12<12;c12++){
      int c = cq*12 + c12;
      size_t oidx;
      if (mode==0){ int b=n/250, t=n%250; oidx = (((size_t)b*48+c)*250+t)*65+pos; }
      else        { int b=n/65,  qq=n%65; oidx = (((size_t)b*48+c)*250+pos)*65+qq; }
      dst[oidx] = acc[c12] + bias[c] + resid[oidx];
    }
  }
}

// ---------------- fused head projection + leaky + ln_clamp, bt tile in LDS ----------
__global__ __launch_bounds__(256) void k_hproj(
    const float* __restrict__ bt, const float* __restrict__ w,
    const float* __restrict__ bias, const float* __restrict__ alpha,
    const float* __restrict__ g, const float* __restrict__ beta,
    float* __restrict__ dst, int dim, int kt_mode){
  __shared__ float tsh[3120];
  __shared__ float ybuf[780];
  __shared__ float r1[256];
  __shared__ float r2[256];
  int bx = blockIdx.x;          // (h*2+b)*250+t
  int h = bx/500; int rem = bx - h*500; int b = rem/250; int t = rem - b*250;
  int ny = dim*65;
  int tid = threadIdx.x;
  const float* bbase = bt + (size_t)b*48*250*65 + (size_t)t*65;
  for (int kidx=tid; kidx<3120; kidx+=256){
    int c = kidx/65, f = kidx - c*65;
    tsh[kidx] = bbase[(size_t)c*250*65 + f];
  }
  __syncthreads();
  float al = alpha[h];
  float s=0.f, ss=0.f;
  for (int kidx=tid; kidx<ny; kidx+=256){
    int e = kidx/65, f = kidx - e*65;
    const float* wr = w + (h*dim+e)*48;
    float acc = bias[h*dim+e];
    for (int c=0;c<48;c++) acc += tsh[c*65+f]*wr[c];
    if (acc < 0.f) acc *= al;
    ybuf[kidx] = acc; s += acc; ss += acc*acc;
  }
  r1[tid]=s; r2[tid]=ss; __syncthreads();
  for (int st=128; st>0; st>>=1){
    if (tid<st){ r1[tid]+=r1[tid+st]; r2[tid]+=r2[tid+st]; }
    __syncthreads();
  }
  float mu = r1[0]/(float)ny, var = r2[0]/(float)ny - mu*mu;
  float rs = rsqrtf(fmaxf(var, EPSV));
  for (int kidx=tid; kidx<ny; kidx+=256){
    float y = (ybuf[kidx]-mu)*rs*g[h*ny+kidx] + beta[h*ny+kidx];
    if (kt_mode) dst[((size_t)(h*2+b)*520 + kidx)*250 + t] = y;
    else         dst[(size_t)bx*ny + kidx] = y;
  }
}

// ---------------- flattened-head attention v2: block per (hb, 10-t tile) ----------------
__global__ __launch_bounds__(256) void k_headattn2(
    const float* __restrict__ Qp, const float* __restrict__ KT,
    const float* __restrict__ Vp, float* __restrict__ Vo){
  __shared__ float qsh[10*520];
  __shared__ float psh[10*250];
  __shared__ float rinv[10];
  int t0 = blockIdx.x*10;
  int hb = blockIdx.y;
  int h = hb >> 1, b = hb & 1;
  int tid = threadIdx.x;
  const float* qbase = Qp + ((size_t)hb*250 + t0)*520;
  for (int i=tid; i<5200; i+=256) qsh[i] = qbase[i];
  __syncthreads();
  const float scale = 0.04385290096535147f; // 1/sqrt(520)
  if (tid < 250){
    float sc[10];
    #pragma unroll
    for (int i=0;i<10;i++) sc[i]=0.f;
    const float* kcol = KT + (size_t)hb*520*250 + tid;
    for (int d=0; d<520; d++){
      float kv = kcol[(size_t)d*250];
      #pragma unroll
      for (int i=0;i<10;i++) sc[i] += qsh[i*520+d]*kv;
    }
    #pragma unroll
    for (int i=0;i<10;i++) psh[i*250+tid] = sc[i]*scale;
  }
  __syncthreads();
  if (tid < 10){
    float m = -1e30f;
    for (int s2=0;s2<250;s2++) m = fmaxf(m, psh[tid*250+s2]);
    float den = 0.f;
    for (int s2=0;s2<250;s2++){
      float e = __expf(psh[tid*250+s2]-m);
      psh[tid*250+s2]=e; den+=e;
    }
    rinv[tid] = 1.0f/den;
  }
  __syncthreads();
  float acc[10][4];
  #pragma unroll
  for (int i=0;i<10;i++)
    #pragma unroll
    for (int s=0;s<4;s++) acc[i][s]=0.f;
  for (int s2=0; s2<250; s2++){
    const float* vrow = Vp + ((size_t)hb*250 + s2)*780;
    float p[10];
    #pragma unroll
    for (int i=0;i<10;i++) p[i] = psh[i*250+s2];
    #pragma unroll
    for (int slot=0; slot<4; slot++){
      int d = tid + slot*256;
      if (d < 780){
        float v = vrow[d];
        #pragma unroll
        for (int i=0;i<10;i++) acc[i][slot] += p[i]*v;
      }
    }
  }
  #pragma unroll
  for (int slot=0; slot<4; slot++){
    int d = tid + slot*256;
    if (d < 780){
      int e = d/65, f = d - e*65;
      #pragma unroll
      for (int i=0;i<10;i++){
        Vo[(((size_t)b*48 + h*12 + e)*250 + (t0+i))*65 + f] = acc[i][slot]*rinv[i];
      }
    }
  }
}

// ---------------- fused p-projection + leaky + ln_clamp + residual ----------------
__global__ __launch_bounds__(256) void k_pprojln(
    const float* __restrict__ Vo, const float* __restrict__ pw,
    const float* __restrict__ pb, const float* __restrict__ pa,
    const float* __restrict__ pg, const float* __restrict__ pbt,
    const float* __restrict__ inter, float* __restrict__ outb){
  __shared__ float vsh[3120];
  __shared__ float ysh[3120];
  __shared__ float r1[256];
  __shared__ float r2[256];
  int bx = blockIdx.x;
  int t = bx % 250, b = bx/250;
  int tid = threadIdx.x;
  const float* vbase = Vo + (size_t)b*48*250*65 + (size_t)t*65;
  for (int k=tid; k<3120; k+=256){
    int c = k/65, f = k - c*65;
    vsh[k] = vbase[(size_t)c*250*65 + f];
  }
  __syncthreads();
  float pav = pa[0];
  float s=0.f, ss=0.f;
  for (int k=tid; k<3120; k+=256){
    int o = k/65, f = k - o*65;
    const float* wr = pw + o*48;
    float acc = pb[o];
    for (int c=0;c<48;c++) acc += vsh[c*65+f]*wr[c];
    if (acc < 0.f) acc *= pav;
    ysh[k] = acc; s += acc; ss += acc*acc;
  }
  r1[tid]=s; r2[tid]=ss; __syncthreads();
  for (int st=128; st>0; st>>=1){
    if (tid<st){ r1[tid]+=r1[tid+st]; r2[tid]+=r2[tid+st]; }
    __syncthreads();
  }
  float mu = r1[0]*(1.0f/3120.0f), var = r2[0]*(1.0f/3120.0f) - mu*mu;
  float rs = rsqrtf(fmaxf(var, EPSV));
  for (int k=tid; k<3120; k+=256){
    int c = k/65, f = k - c*65;
    size_t idx = (((size_t)b*48+c)*250 + t)*65 + f;
    outb[idx] = (ysh[k]-mu)*rs*pg[k] + pbt[k] + inter[idx];
  }
}

// ---------------- fin 1x1 (48->384), 4 outputs/thread ----------------
__global__ void k_fin2(const float* __restrict__ outb, const float* __restrict__ w,
                       const float* __restrict__ bias, float* __restrict__ pi){
  int i = blockIdx.x*blockDim.x + threadIdx.x;
  if (i >= 2*96*250*65) return;
  int f = i % 65;
  int t = (i/65) % 250;
  int og = (i/(65*250)) % 96;
  int b = i/(65*250*96);
  const float* xp = outb + (size_t)b*48*250*65 + (size_t)t*65 + f;
  const float* w0 = w + og*4*48;
  float a0=bias[og*4], a1=bias[og*4+1], a2=bias[og*4+2], a3=bias[og*4+3];
  for (int c=0;c<48;c++){
    float xv = xp[(size_t)c*250*65];
    a0 += xv*w0[c]; a1 += xv*w0[48+c]; a2 += xv*w0[96+c]; a3 += xv*w0[144+c];
  }
  size_t o0 = (((size_t)b*384 + og*4)*250 + t)*65 + f;
  pi[o0] = a0; pi[o0+16250] = a1; pi[o0+2*16250] = a2; pi[o0+3*16250] = a3;
}

// ---------------- depthwise 3x3 both halves + gelu-gate ----------------
__global__ void k_dwg(const float* __restrict__ pi, const float* __restrict__ dw,
                      const float* __restrict__ db, float* __restrict__ gbuf){
  int i = blockIdx.x*blockDim.x + threadIdx.x;
  if (i >= 2*192*250*65) return;
  int f = i % 65;
  int t = (i/65) % 250;
  int j = (i/(65*250)) % 192;
  int b = i/(65*250*192);
  float x12[2];
  for (int half=0; half<2; half++){
    int ch = j + half*192;
    const float* base = pi + ((size_t)b*384 + ch)*250*65;
    const float* wr = dw + ch*9;
    float acc = db[ch];
    for (int dt=-1; dt<=1; dt++){
      int tt = t+dt;
      if (tt<0||tt>=250) continue;
      for (int df=-1; df<=1; df++){
        int ff = f+df;
        if (ff<0||ff>=65) continue;
        acc += base[(size_t)tt*65+ff]*wr[(dt+1)*3 + (df+1)];
      }
    }
    x12[half]=acc;
  }
  float x1 = x12[0];
  float g = 0.5f*x1*(1.0f+erff(x1*0.70710678118654752f));
  gbuf[i] = g * x12[1];
}

// ---------------- final 1x1 (192->48), 4 outputs/thread, + residual -> d_out ----------------
__global__ void k_final2(const float* __restrict__ gbuf, const float* __restrict__ w,
                         const float* __restrict__ bias, const float* __restrict__ outb,
                         float* __restrict__ dout){
  int i = blockIdx.x*blockDim.x + threadIdx.x;
  if (i >= 2*12*250*65) return;
  int f = i % 65;
  int t = (i/65) % 250;
  int og = (i/(65*250)) % 12;
  int b = i/(65*250*12);
  const float* gp = gbuf + (size_t)b*192*250*65 + (size_t)t*65 + f;
  const float* w0 = w + og*4*192;
  float a0=bias[og*4], a1=bias[og*4+1], a2=bias[og*4+2], a3=bias[og*4+3];
  for (int j=0;j<192;j++){
    float gv = gp[(size_t)j*250*65];
    a0 += gv*w0[j]; a1 += gv*w0[192+j]; a2 += gv*w0[384+j]; a3 += gv*w0[576+j];
  }
  size_t o0 = (((size_t)b*48 + og*4)*250 + t)*65 + f;
  dout[o0]         = a0 + outb[o0];
  dout[o0+16250]   = a1 + outb[o0+16250];
  dout[o0+2*16250] = a2 + outb[o0+2*16250];
  dout[o0+3*16250] = a3 + outb[o0+3*16250];
}

extern "C" void kernel_launch(void* const* d_in, const int* in_sizes, int n_in,
                              void* d_out, int out_size, void* d_ws, size_t ws_size,
                              hipStream_t stream) {
  (void)in_sizes; (void)n_in; (void)out_size; (void)ws_size;
  auto in = [&](int i){ return (const float*)d_in[i]; };
  const float* x        = in(0);
  const float* af_in_w  = in(1);  const float* af_in_b  = in(2);
  const float* af_out_w = in(3);  const float* af_out_b = in(4);
  const float* at_in_w  = in(5);  const float* at_in_b  = in(6);
  const float* at_out_w = in(7);  const float* at_out_b = in(8);
  const float* naf_g = in(9),  *naf_b = in(10), *nat_g = in(11), *nat_b = in(12);
  const float* intra_ng = in(13), *intra_nb = in(14), *inter_ng = in(15), *inter_nb = in(16);
  const float* intra_wif = in(17), *intra_whf = in(18), *intra_bif = in(19), *intra_bhf = in(20);
  const float* intra_wib = in(21), *intra_whb = in(22), *intra_bib = in(23), *intra_bhb = in(24);
  const float* inter_wif = in(25), *inter_whf = in(26), *inter_bif = in(27), *inter_bhf = in(28);
  const float* inter_wib = in(29), *inter_whb = in(30), *inter_bib = in(31), *inter_bhb = in(32);
  const float* il_w = in(33), *il_b = in(34), *itl_w = in(35), *itl_b = in(36);
  const float* qw = in(37), *qb = in(38), *qa = in(39), *qg = in(40), *qbt = in(41);
  const float* kw = in(42), *kb = in(43), *ka = in(44), *kg = in(45), *kbt = in(46);
  const float* vw = in(47), *vb = in(48), *va = in(49), *vg = in(50), *vbt = in(51);
  const float* pw = in(52), *pb = in(53), *pa = in(54), *pg = in(55), *pbt = in(56);
  const float* fin_w = in(57), *fin_b = in(58), *fdw_w = in(59), *fdw_b = in(60);
  const float* fout_w = in(61), *fout_b = in(62);

  float* ws = (float*)d_ws;
  float* buf_intra = ws + 0;                        // 1,560,000
  float* buf_bt    = ws + 1560000;                  // 1,560,000
  float* buf_out   = ws + 3120000;                  // 1,560,000
  unsigned int* wpk = (unsigned int*)(ws + 4680000);// 8*73728
  unsigned int* wtp = (unsigned int*)(ws + 5269824);// 2*36864
  float* scr       = ws + 5343552;                  // arena
  // staging
  float* s_seq2 = scr;                              // 1,560,000
  float* s_seq  = scr + 1560000;                    // 1,560,000
  float* s_att  = scr + 3120000;                    // 1,560,000
  // lstm buffers
  _Float16* s_pre = (_Float16*)(scr + 4680000);     // up to 49,320,960 halfs
  unsigned int* s_rT2 = (unsigned int*)(scr + 29340480); // up to 6,165,120 uints
  // phase3 aliases
  float* s_Qh = scr;                                // 1,040,000
  float* s_KT = scr + 1040000;                      // 1,040,000
  float* s_Vh = scr + 2080000;                      // 1,560,000
  float* s_Vo = scr + 3640000;                      // 1,560,000
  // phase4 aliases
  float* s_pi = scr;
  float* s_g  = scr + 12480000;

  const int thr = 256;
  auto cdiv = [](int a, int b){ return (a+b-1)/b; };

  // ---------------- weight prep (single kernel) ----------------
  k_prep<<<cdiv(663552,thr),thr,0,stream>>>(
      intra_wif, intra_whf, intra_wib, intra_whb,
      inter_wif, inter_whf, inter_wib, inter_whb,
      il_w, itl_w, wpk, wtp);

  // ---------------- Phase 1: intra (along Q): N=500, L2=62, SL=65 ----------------
  k_ln_chan<<<cdiv(2*250*65,thr), thr, 0, stream>>>(x, s_seq, intra_ng, intra_nb, 0);
  k_mha2<<<dim3(500,4), 256, 0, stream>>>(s_seq, af_in_w, af_in_b, s_att, 500, 65);
  k_projres<<<cdiv(500*65*48,thr), thr, 0, stream>>>(s_att, s_seq, af_out_w, af_out_b, s_seq2, 500*65);
  k_rowln<<<cdiv(32500,thr), thr, 0, stream>>>(s_seq2, naf_g, naf_b, 32500);
  {
    const size_t dstr = (size_t)500*62*768;
    k_pregates<<<dim3(4,500), 256, 0, stream>>>(s_seq2, wpk+0*73728, intra_bif, intra_bhf, s_pre,        62, 65);
    k_pregates<<<dim3(4,500), 256, 0, stream>>>(s_seq2, wpk+2*73728, intra_bib, intra_bhb, s_pre + dstr, 62, 65);
  }
  k_lstm11<2><<<dim3(250,2), 512, 0, stream>>>(s_pre, s_rT2, wpk+1*73728, wpk+3*73728, 500, 62);
  k_convt4<<<dim3(2,500), 256, 0, stream>>>(s_rT2, wtp+0*36864, il_b, x, buf_intra, 62, 65, 0);

  // ---------------- Phase 2: inter (along T): N=130, L2=247, SL=250 ----------------
  k_ln_chan<<<cdiv(2*250*65,thr),thr,0,stream>>>(buf_intra, s_seq, inter_ng, inter_nb, 1);
  k_mha2<<<dim3(130,4), 256, 0, stream>>>(s_seq, at_in_w, at_in_b, s_att, 130, 250);
  k_projres<<<cdiv(130*250*48,thr),thr,0,stream>>>(s_att, s_seq, at_out_w, at_out_b, s_seq2, 130*250);
  k_rowln<<<cdiv(32500,thr),thr,0,stream>>>(s_seq2, nat_g, nat_b, 32500);
  {
    const size_t dstr = (size_t)130*247*768;
    k_pregates<<<dim3(16,130), 256, 0, stream>>>(s_seq2, wpk+4*73728, inter_bif, inter_bhf, s_pre,        247, 250);
    k_pregates<<<dim3(16,130), 256, 0, stream>>>(s_seq2, wpk+6*73728, inter_bib, inter_bhb, s_pre + dstr, 247, 250);
  }
  k_lstm11<1><<<dim3(130,2), 512, 0, stream>>>(s_pre, s_rT2, wpk+5*73728, wpk+7*73728, 130, 247);
  k_convt4<<<dim3(4,130), 256, 0, stream>>>(s_rT2, wtp+1*36864, itl_b, buf_intra, buf_bt, 247, 250, 1);

  // ---------------- Phase 3: flattened-head attention ----------------
  k_hproj<<<2000,256,0,stream>>>(buf_bt, qw, qb, qa, qg, qbt, s_Qh, 8, 0);
  k_hproj<<<2000,256,0,stream>>>(buf_bt, kw, kb, ka, kg, kbt, s_KT, 8, 1);
  k_hproj<<<2000,256,0,stream>>>(buf_bt, vw, vb, va, vg, vbt, s_Vh, 12, 0);
  k_headattn2<<<dim3(25,8), 256, 0, stream>>>(s_Qh, s_KT, s_Vh, s_Vo);
  k_pprojln<<<500,256,0,stream>>>(s_Vo, pw, pb, pa, pg, pbt, buf_bt, buf_out);

  // ---------------- Phase 4: FFN ----------------
  k_fin2<<<cdiv(2*96*250*65,thr),thr,0,stream>>>(buf_out, fin_w, fin_b, s_pi);
  k_dwg<<<cdiv(2*192*250*65,thr),thr,0,stream>>>(s_pi, fdw_w, fdw_b, s_g);
  k_final2<<<cdiv(2*12*250*65,thr),thr,0,stream>>>(s_g, fout_w, fout_b, buf_out, (float*)d_out);
}

// Round 12
// 3323.287 us; speedup vs baseline: 1.0350x; 1.0350x over previous
//
#include <hip/hip_runtime.h>
#include <math.h>

#define EPSV 1e-5f

typedef _Float16 v2h __attribute__((ext_vector_type(2)));

__device__ __forceinline__ float sigf(float x){ return 1.0f/(1.0f+__expf(-x)); }
__device__ __forceinline__ float tanhf_(float x){
  float c = fminf(fmaxf(x,-10.f),10.f);
  float e = __expf(2.0f*c);
  return (e-1.0f)/(e+1.0f);
}

// LDS-only barrier: drains lgkmcnt but NOT vmcnt.
__device__ __forceinline__ void ldsbar(){
  asm volatile("s_waitcnt lgkmcnt(0)\n\ts_barrier" ::: "memory");
}

__device__ __forceinline__ float dot2u(unsigned int a, unsigned int b, float c){
#if __has_builtin(__builtin_amdgcn_fdot2)
  v2h av = __builtin_bit_cast(v2h, a);
  v2h bv = __builtin_bit_cast(v2h, b);
  return __builtin_amdgcn_fdot2(av, bv, c, false);
#else
  v2h av = __builtin_bit_cast(v2h, a);
  v2h bv = __builtin_bit_cast(v2h, b);
  return c + (float)av.x*(float)bv.x + (float)av.y*(float)bv.y;
#endif
}

// ---------------- LN over channel dim -> channel-last seq ----------------
__global__ void k_ln_chan(const float* __restrict__ src, float* __restrict__ dst,
                          const float* __restrict__ g, const float* __restrict__ bb, int mode){
  int i = blockIdx.x*blockDim.x + threadIdx.x;
  const int total = 2*250*65;
  if (i >= total) return;
  int q = i % 65; int t = (i/65) % 250; int b = i/(65*250);
  const float* p = src + (size_t)b*48*250*65 + (size_t)t*65 + q;
  float s=0.f, ss=0.f;
  for (int c=0;c<48;c++){ float v = p[(size_t)c*250*65]; s+=v; ss+=v*v; }
  float mu = s*(1.0f/48.0f);
  float var = ss*(1.0f/48.0f) - mu*mu;
  float rs = rsqrtf(fmaxf(var, EPSV));
  float* d = (mode==0) ? dst + ((size_t)(b*250+t)*65 + q)*48
                       : dst + ((size_t)(b*65+q)*250 + t)*48;
  for (int c=0;c<48;c++){ float v = p[(size_t)c*250*65]; d[c] = (v-mu)*rs*g[c] + bb[c]; }
}

// ---------------- fused qkv + MHA: block per (n,h), qkv computed in-block ----------------
__global__ __launch_bounds__(256) void k_mha2(
    const float* __restrict__ seq, const float* __restrict__ inw,
    const float* __restrict__ inb, float* __restrict__ att, int N, int L){
  __shared__ float shq[250*12];
  __shared__ float shk[250*12];
  __shared__ float shv[250*12];
  int n = blockIdx.x, h = blockIdx.y;
  for (int i = threadIdx.x; i < L*36; i += 256){
    int l = i/36, jj = i - (i/36)*36;
    int sect = jj/12, d = jj - sect*12;
    int j = sect*48 + h*12 + d;
    const float* srow = seq + ((size_t)n*L + l)*48;
    const float* wrow = inw + j*48;
    float acc = inb[j];
    for (int c=0;c<48;c++) acc += srow[c]*wrow[c];
    float* dst = (sect==0)?shq:(sect==1)?shk:shv;
    dst[l*12+d] = acc;
  }
  __syncthreads();
  const float scale = 0.28867513459481287f;
  for (int r = threadIdx.x; r < L; r += 256){
    const float4* q4 = (const float4*)(shq + r*12);
    float4 q0 = q4[0], q1 = q4[1], q2 = q4[2];
    float m = -1e30f, den = 0.0f;
    float4 o0 = make_float4(0,0,0,0), o1 = make_float4(0,0,0,0), o2 = make_float4(0,0,0,0);
    for (int j=0; j<L; j++){
      const float4* k4 = (const float4*)(shk + j*12);
      float4 k0 = k4[0], k1 = k4[1], k2 = k4[2];
      float s = q0.x*k0.x + q0.y*k0.y + q0.z*k0.z + q0.w*k0.w
              + q1.x*k1.x + q1.y*k1.y + q1.z*k1.z + q1.w*k1.w
              + q2.x*k2.x + q2.y*k2.y + q2.z*k2.z + q2.w*k2.w;
      s *= scale;
      if (s > m){
        float corr = __expf(m - s);
        den *= corr;
        o0.x*=corr; o0.y*=corr; o0.z*=corr; o0.w*=corr;
        o1.x*=corr; o1.y*=corr; o1.z*=corr; o1.w*=corr;
        o2.x*=corr; o2.y*=corr; o2.z*=corr; o2.w*=corr;
        m = s;
      }
      float e = __expf(s - m);
      den += e;
      const float4* v4 = (const float4*)(shv + j*12);
      float4 v0 = v4[0], v1 = v4[1], v2 = v4[2];
      o0.x += e*v0.x; o0.y += e*v0.y; o0.z += e*v0.z; o0.w += e*v0.w;
      o1.x += e*v1.x; o1.y += e*v1.y; o1.z += e*v1.z; o1.w += e*v1.w;
      o2.x += e*v2.x; o2.y += e*v2.y; o2.z += e*v2.z; o2.w += e*v2.w;
    }
    float inv = 1.0f/den;
    float* outp = att + ((size_t)n*L + r)*48 + h*12;
    outp[0]=o0.x*inv; outp[1]=o0.y*inv; outp[2]=o0.z*inv; outp[3]=o0.w*inv;
    outp[4]=o1.x*inv; outp[5]=o1.y*inv; outp[6]=o1.z*inv; outp[7]=o1.w*inv;
    outp[8]=o2.x*inv; outp[9]=o2.y*inv; outp[10]=o2.z*inv; outp[11]=o2.w*inv;
  }
}

// ---------------- out proj + residual ----------------
__global__ void k_projres(const float* __restrict__ att, const float* __restrict__ seq,
                          const float* __restrict__ w, const float* __restrict__ bias,
                          float* __restrict__ dst, int NL){
  int i = blockIdx.x*blockDim.x + threadIdx.x;
  if (i >= NL*48) return;
  int o = i % 48; int nl = i/48;
  const float* ar = att + (size_t)nl*48;
  const float* wr = w + o*48;
  float acc = bias[o] + seq[i];
  for (int c=0;c<48;c++) acc += ar[c]*wr[c];
  dst[i] = acc;
}

// ---------------- torch_ln over last dim (48), in place ----------------
__global__ void k_rowln(float* __restrict__ buf, const float* __restrict__ g,
                        const float* __restrict__ bb, int NL){
  int nl = blockIdx.x*blockDim.x + threadIdx.x;
  if (nl >= NL) return;
  float* p = buf + (size_t)nl*48;
  float s=0.f, ss=0.f;
  for (int c=0;c<48;c++){ float v=p[c]; s+=v; ss+=v*v; }
  float mu = s*(1.0f/48.0f);
  float var = ss*(1.0f/48.0f) - mu*mu;
  float rs = rsqrtf(var + EPSV);
  for (int c=0;c<48;c++) p[c] = (p[c]-mu)*rs*g[c] + bb[c];
}

// ---------------- fused weight prep: 8x lstm wpack + 2x convT f16-pack ----------------
__global__ void k_prep(const float* __restrict__ s0, const float* __restrict__ s1,
                       const float* __restrict__ s2, const float* __restrict__ s3,
                       const float* __restrict__ s4, const float* __restrict__ s5,
                       const float* __restrict__ s6, const float* __restrict__ s7,
                       const float* __restrict__ c0, const float* __restrict__ c1,
                       unsigned int* __restrict__ wpk, unsigned int* __restrict__ wtp){
  int i = blockIdx.x*blockDim.x + threadIdx.x;
  if (i < 589824){
    int seg = i/73728, off = i - seg*73728;
    const float* w = (seg==0)?s0:(seg==1)?s1:(seg==2)?s2:(seg==3)?s3:(seg==4)?s4:(seg==5)?s5:(seg==6)?s6:s7;
    int g = off % 768, d2 = off / 768;
    v2h v; v.x = (_Float16)w[g*192 + 2*d2]; v.y = (_Float16)w[g*192 + 2*d2 + 1];
    wpk[(size_t)seg*73728 + (size_t)d2*768 + g] = __builtin_bit_cast(unsigned int, v);
  } else if (i < 589824 + 2*36864){
    int j = i - 589824;
    int seg = j/36864, off = j - seg*36864;
    const float* w = seg ? c1 : c0;
    int c = off % 48; int ii2 = (off/48) % 192; int k = off/(48*192);
    v2h v;
    v.x = (_Float16)w[(2*ii2)*192 + c*4 + k];
    v.y = (_Float16)w[(2*ii2+1)*192 + c*4 + k];
    wtp[(size_t)seg*36864 + off] = __builtin_bit_cast(unsigned int, v);
  }
}

// ---------------- pre-gates GEMM: pre[n][l][g] = u.wi^T + bi + bh (f16 out) ----------------
__global__ __launch_bounds__(256) void k_pregates(
    const float* __restrict__ seq2, const unsigned int* __restrict__ wi,
    const float* __restrict__ bi, const float* __restrict__ bh,
    _Float16* __restrict__ pre, int L2, int SL){
  __shared__ unsigned int ut[96*16];
  int n = blockIdx.y;
  int l0 = blockIdx.x*16;
  int t = threadIdx.x;
  for (int idx=t; idx<1536; idx+=256){
    int l = idx & 15, d2 = idx >> 4;
    int li = l0 + l;
    int c = d2 >> 1, k0 = (d2 & 1)*2;
    float u0=0.f, u1=0.f;
    if (li < L2){
      const float* p = seq2 + ((size_t)n*SL + li)*48;
      u0 = p[k0*48 + c];
      u1 = p[(k0+1)*48 + c];
    }
    v2h v; v.x=(_Float16)u0; v.y=(_Float16)u1;
    ut[d2*16 + l] = __builtin_bit_cast(unsigned int, v);
  }
  __syncthreads();
  float acc[3][16];
  float b0 = bi[t] + bh[t];
  float b1 = bi[t+256] + bh[t+256];
  float b2 = bi[t+512] + bh[t+512];
  #pragma unroll
  for (int l=0;l<16;l++){ acc[0][l]=b0; acc[1][l]=b1; acc[2][l]=b2; }
  #pragma unroll 4
  for (int d2=0; d2<96; d2++){
    unsigned int w0 = wi[(size_t)d2*768 + t];
    unsigned int w1 = wi[(size_t)d2*768 + t + 256];
    unsigned int w2 = wi[(size_t)d2*768 + t + 512];
    const uint4* u4 = (const uint4*)(ut + d2*16);
    #pragma unroll
    for (int l4=0; l4<4; l4++){
      uint4 uu = u4[l4];
      acc[0][l4*4+0] = dot2u(uu.x, w0, acc[0][l4*4+0]);
      acc[0][l4*4+1] = dot2u(uu.y, w0, acc[0][l4*4+1]);
      acc[0][l4*4+2] = dot2u(uu.z, w0, acc[0][l4*4+2]);
      acc[0][l4*4+3] = dot2u(uu.w, w0, acc[0][l4*4+3]);
      acc[1][l4*4+0] = dot2u(uu.x, w1, acc[1][l4*4+0]);
      acc[1][l4*4+1] = dot2u(uu.y, w1, acc[1][l4*4+1]);
      acc[1][l4*4+2] = dot2u(uu.z, w1, acc[1][l4*4+2]);
      acc[1][l4*4+3] = dot2u(uu.w, w1, acc[1][l4*4+3]);
      acc[2][l4*4+0] = dot2u(uu.x, w2, acc[2][l4*4+0]);
      acc[2][l4*4+1] = dot2u(uu.y, w2, acc[2][l4*4+1]);
      acc[2][l4*4+2] = dot2u(uu.z, w2, acc[2][l4*4+2]);
      acc[2][l4*4+3] = dot2u(uu.w, w2, acc[2][l4*4+3]);
    }
  }
  #pragma unroll
  for (int l=0;l<16;l++){
    int li = l0 + l;
    if (li < L2){
      _Float16* pr = pre + ((size_t)n*L2 + li)*768;
      pr[t]       = (_Float16)acc[0][l];
      pr[t+256]   = (_Float16)acc[1][l];
      pr[t+512]   = (_Float16)acc[2][l];
    }
  }
}

// ---------------- biLSTM scan v12: half weights LDS-resident (conflict-free [d2][row]
// layout, b32 reads), half L2-streamed. Halves per-step L2 weight traffic vs lstm6. ----
template<int G>
__global__ __launch_bounds__(512,1) void k_lstm12(
    const _Float16* __restrict__ pre, unsigned int* __restrict__ rT2,
    const unsigned int* __restrict__ wh_f, const unsigned int* __restrict__ wh_b,
    int N, int L2){
  __shared__ unsigned int wsh[48*768];    // [d2][row] — same layout as global (147456 B)
  __shared__ unsigned int hh2[96*G];      // [d2][s] packed h pairs
  __shared__ float gpart[2*G*768];        // [hf][s][row]
  _Float16* hh2h = (_Float16*)hh2;
  int t = threadIdx.x;
  int hf = t >> 8, tt = t & 255;
  int dir = blockIdx.y;
  int n0 = blockIdx.x*G;
  const unsigned int* wh = dir ? wh_b : wh_f;

  // direct coalesced copy of d2 in [0,48)
  for (int idx=t; idx<48*768; idx+=512) wsh[idx] = wh[idx];
  for (int idx=t; idx<96*G; idx+=512) hh2[idx]=0u;

  const _Float16* prd = pre + (size_t)dir*(size_t)N*L2*768;
  float cst = 0.f;
  int as = t/192, aj = t - as*192;
  bool actv = (t < 192*G);
  const unsigned short* pbase = (const unsigned short*)prd;
  if (actv) pbase = (const unsigned short*)(prd + ((size_t)(n0+as)*L2)*768) + aj;
  __syncthreads();

  unsigned short c0=0,c1=0,c2=0,c3=0;
  {
    int l0 = dir ? (L2-1) : 0;
    if (actv){
      const unsigned short* pp = pbase + (size_t)l0*768;
      c0 = pp[0]; c1 = pp[192]; c2 = pp[384]; c3 = pp[576];
    }
  }

  const unsigned int* wstr = wh + 48*768 + tt;   // streamed half base (row tt)

  for (int step=0; step<L2; step++){
    int l = dir ? (L2-1-step) : step;
    int stepn = (step+1 < L2) ? (step+1) : step;
    int ln = dir ? (L2-1-stepn) : stepn;
    unsigned short pn0=0,pn1=0,pn2=0,pn3=0;
    if (actv){
      const unsigned short* pp = pbase + (size_t)ln*768;
      pn0 = pp[0]; pn1 = pp[192]; pn2 = pp[384]; pn3 = pp[576];
    }

    float acc0[G], acc1[G], acc2[G];
    #pragma unroll
    for (int s=0;s<G;s++){ acc0[s]=0.f; acc1[s]=0.f; acc2[s]=0.f; }

    if (hf==0){
      // LDS half: d2 in [0,48). Conflict-free: consecutive lanes -> consecutive words.
      #pragma unroll 8
      for (int i=0;i<48;i++){
        unsigned int h2v[G];
        if (G==1){ h2v[0] = hh2[i]; }
        else {
          uint2 hv = *(const uint2*)&hh2[i*2];
          h2v[0]=hv.x; h2v[1]=hv.y;
        }
        unsigned int w0 = wsh[i*768 + tt];
        unsigned int w1 = wsh[i*768 + tt + 256];
        unsigned int w2 = wsh[i*768 + tt + 512];
        #pragma unroll
        for (int s=0;s<G;s++){
          acc0[s] = dot2u(h2v[s], w0, acc0[s]);
          acc1[s] = dot2u(h2v[s], w1, acc1[s]);
          acc2[s] = dot2u(h2v[s], w2, acc2[s]);
        }
      }
    } else {
      // L2-streamed half: d2 in [48,96)
      #pragma unroll 8
      for (int i=0;i<48;i++){
        unsigned int h2v[G];
        if (G==1){ h2v[0] = hh2[48+i]; }
        else {
          uint2 hv = *(const uint2*)&hh2[(48+i)*2];
          h2v[0]=hv.x; h2v[1]=hv.y;
        }
        unsigned int w0 = wstr[(size_t)i*768];
        unsigned int w1 = wstr[(size_t)i*768 + 256];
        unsigned int w2 = wstr[(size_t)i*768 + 512];
        #pragma unroll
        for (int s=0;s<G;s++){
          acc0[s] = dot2u(h2v[s], w0, acc0[s]);
          acc1[s] = dot2u(h2v[s], w1, acc1[s]);
          acc2[s] = dot2u(h2v[s], w2, acc2[s]);
        }
      }
    }
    #pragma unroll
    for (int s=0;s<G;s++){
      gpart[(hf*G+s)*768 + tt]       = acc0[s];
      gpart[(hf*G+s)*768 + tt + 256] = acc1[s];
      gpart[(hf*G+s)*768 + tt + 512] = acc2[s];
    }
    ldsbar();

    if (actv){
      float gi = (float)__builtin_bit_cast(_Float16, c0);
      float gf = (float)__builtin_bit_cast(_Float16, c1);
      float gg = (float)__builtin_bit_cast(_Float16, c2);
      float go = (float)__builtin_bit_cast(_Float16, c3);
      #pragma unroll
      for (int hh=0; hh<2; hh++){
        const float* gp = gpart + (hh*G+as)*768;
        gi += gp[aj]; gf += gp[aj+192]; gg += gp[aj+384]; go += gp[aj+576];
      }
      float ig = sigf(gi), fg = sigf(gf), g2 = tanhf_(gg), og = sigf(go);
      cst = fg*cst + ig*g2;
      float hn = og*tanhf_(cst);
      hh2h[((aj>>1)*G + as)*2 + (aj&1)] = (_Float16)hn;
    }
    ldsbar();

    if (t < 96*G){
      int s = t/96, ii2 = t - s*96;
      unsigned int v = hh2[ii2*G + s];
      rT2[((size_t)(n0+s)*192 + dir*96 + ii2)*L2 + l] = v;
    }
    c0 = pn0; c1 = pn1; c2 = pn2; c3 = pn3;
  }
}

// ---------------- conv_transpose1d v4: scalar (SMEM) weights, coalesced rT2 reads -------
__global__ __launch_bounds__(256) void k_convt4(
    const unsigned int* __restrict__ rT2, const unsigned int* __restrict__ wtp,
    const float* __restrict__ bias, const float* __restrict__ resid,
    float* __restrict__ dst, int L2, int OL, int mode){
  int n = blockIdx.y;
  int pos = blockIdx.x*64 + (threadIdx.x & 63);
  int cq = __builtin_amdgcn_readfirstlane((int)(threadIdx.x >> 6));
  float acc[12];
  #pragma unroll
  for (int c=0;c<12;c++) acc[c]=0.f;
  const unsigned int* rbase = rT2 + (size_t)n*192*L2;
  for (int k=0;k<4;k++){
    int l = pos - k;
    bool v = (l>=0) && (l<L2);
    int lc = v ? l : 0;
    const unsigned int* wk = wtp + (size_t)k*192*48 + cq*12;
    #pragma unroll 4
    for (int ii2=0; ii2<192; ii2++){
      unsigned int rp = v ? rbase[(size_t)ii2*L2 + lc] : 0u;
      const unsigned int* wrow = wk + ii2*48;
      #pragma unroll
      for (int c=0;c<12;c++) acc[c] = dot2u(rp, wrow[c], acc[c]);
    }
  }
  if (pos < OL){
    for (int c12=0;c12<12;c12++){
      int c = cq*12 + c12;
      size_t oidx;
      if (mode==0){ int b=n/250, t=n%250; oidx = (((size_t)b*48+c)*250+t)*65+pos; }
      else        { int b=n/65,  qq=n%65; oidx = (((size_t)b*48+c)*250+pos)*65+qq; }
      dst[oidx] = acc[c12] + bias[c] + resid[oidx];
    }
  }
}

// ---------------- fused head projection + leaky + ln_clamp, bt tile in LDS ----------
__global__ __launch_bounds__(256) void k_hproj(
    const float* __restrict__ bt, const float* __restrict__ w,
    const float* __restrict__ bias, const float* __restrict__ alpha,
    const float* __restrict__ g, const float* __restrict__ beta,
    float* __restrict__ dst, int dim, int kt_mode){
  __shared__ float tsh[3120];
  __shared__ float ybuf[780];
  __shared__ float r1[256];
  __shared__ float r2[256];
  int bx = blockIdx.x;          // (h*2+b)*250+t
  int h = bx/500; int rem = bx - h*500; int b = rem/250; int t = rem - b*250;
  int ny = dim*65;
  int tid = threadIdx.x;
  const float* bbase = bt + (size_t)b*48*250*65 + (size_t)t*65;
  for (int kidx=tid; kidx<3120; kidx+=256){
    int c = kidx/65, f = kidx - c*65;
    tsh[kidx] = bbase[(size_t)c*250*65 + f];
  }
  __syncthreads();
  float al = alpha[h];
  float s=0.f, ss=0.f;
  for (int kidx=tid; kidx<ny; kidx+=256){
    int e = kidx/65, f = kidx - e*65;
    const float* wr = w + (h*dim+e)*48;
    float acc = bias[h*dim+e];
    for (int c=0;c<48;c++) acc += tsh[c*65+f]*wr[c];
    if (acc < 0.f) acc *= al;
    ybuf[kidx] = acc; s += acc; ss += acc*acc;
  }
  r1[tid]=s; r2[tid]=ss; __syncthreads();
  for (int st=128; st>0; st>>=1){
    if (tid<st){ r1[tid]+=r1[tid+st]; r2[tid]+=r2[tid+st]; }
    __syncthreads();
  }
  float mu = r1[0]/(float)ny, var = r2[0]/(float)ny - mu*mu;
  float rs = rsqrtf(fmaxf(var, EPSV));
  for (int kidx=tid; kidx<ny; kidx+=256){
    float y = (ybuf[kidx]-mu)*rs*g[h*ny+kidx] + beta[h*ny+kidx];
    if (kt_mode) dst[((size_t)(h*2+b)*520 + kidx)*250 + t] = y;
    else         dst[(size_t)bx*ny + kidx] = y;
  }
}

// ---------------- flattened-head attention v2: block per (hb, 10-t tile) ----------------
__global__ __launch_bounds__(256) void k_headattn2(
    const float* __restrict__ Qp, const float* __restrict__ KT,
    const float* __restrict__ Vp, float* __restrict__ Vo){
  __shared__ float qsh[10*520];
  __shared__ float psh[10*250];
  __shared__ float rinv[10];
  int t0 = blockIdx.x*10;
  int hb = blockIdx.y;
  int h = hb >> 1, b = hb & 1;
  int tid = threadIdx.x;
  const float* qbase = Qp + ((size_t)hb*250 + t0)*520;
  for (int i=tid; i<5200; i+=256) qsh[i] = qbase[i];
  __syncthreads();
  const float scale = 0.04385290096535147f; // 1/sqrt(520)
  if (tid < 250){
    float sc[10];
    #pragma unroll
    for (int i=0;i<10;i++) sc[i]=0.f;
    const float* kcol = KT + (size_t)hb*520*250 + tid;
    for (int d=0; d<520; d++){
      float kv = kcol[(size_t)d*250];
      #pragma unroll
      for (int i=0;i<10;i++) sc[i] += qsh[i*520+d]*kv;
    }
    #pragma unroll
    for (int i=0;i<10;i++) psh[i*250+tid] = sc[i]*scale;
  }
  __syncthreads();
  if (tid < 10){
    float m = -1e30f;
    for (int s2=0;s2<250;s2++) m = fmaxf(m, psh[tid*250+s2]);
    float den = 0.f;
    for (int s2=0;s2<250;s2++){
      float e = __expf(psh[tid*250+s2]-m);
      psh[tid*250+s2]=e; den+=e;
    }
    rinv[tid] = 1.0f/den;
  }
  __syncthreads();
  float acc[10][4];
  #pragma unroll
  for (int i=0;i<10;i++)
    #pragma unroll
    for (int s=0;s<4;s++) acc[i][s]=0.f;
  for (int s2=0; s2<250; s2++){
    const float* vrow = Vp + ((size_t)hb*250 + s2)*780;
    float p[10];
    #pragma unroll
    for (int i=0;i<10;i++) p[i] = psh[i*250+s2];
    #pragma unroll
    for (int slot=0; slot<4; slot++){
      int d = tid + slot*256;
      if (d < 780){
        float v = vrow[d];
        #pragma unroll
        for (int i=0;i<10;i++) acc[i][slot] += p[i]*v;
      }
    }
  }
  #pragma unroll
  for (int slot=0; slot<4; slot++){
    int d = tid + slot*256;
    if (d < 780){
      int e = d/65, f = d - e*65;
      #pragma unroll
      for (int i=0;i<10;i++){
        Vo[(((size_t)b*48 + h*12 + e)*250 + (t0+i))*65 + f] = acc[i][slot]*rinv[i];
      }
    }
  }
}

// ---------------- fused p-projection + leaky + ln_clamp + residual ----------------
__global__ __launch_bounds__(256) void k_pprojln(
    const float* __restrict__ Vo, const float* __restrict__ pw,
    const float* __restrict__ pb, const float* __restrict__ pa,
    const float* __restrict__ pg, const float* __restrict__ pbt,
    const float* __restrict__ inter, float* __restrict__ outb){
  __shared__ float vsh[3120];
  __shared__ float ysh[3120];
  __shared__ float r1[256];
  __shared__ float r2[256];
  int bx = blockIdx.x;
  int t = bx % 250, b = bx/250;
  int tid = threadIdx.x;
  const float* vbase = Vo + (size_t)b*48*250*65 + (size_t)t*65;
  for (int k=tid; k<3120; k+=256){
    int c = k/65, f = k - c*65;
    vsh[k] = vbase[(size_t)c*250*65 + f];
  }
  __syncthreads();
  float pav = pa[0];
  float s=0.f, ss=0.f;
  for (int k=tid; k<3120; k+=256){
    int o = k/65, f = k - o*65;
    const float* wr = pw + o*48;
    float acc = pb[o];
    for (int c=0;c<48;c++) acc += vsh[c*65+f]*wr[c];
    if (acc < 0.f) acc *= pav;
    ysh[k] = acc; s += acc; ss += acc*acc;
  }
  r1[tid]=s; r2[tid]=ss; __syncthreads();
  for (int st=128; st>0; st>>=1){
    if (tid<st){ r1[tid]+=r1[tid+st]; r2[tid]+=r2[tid+st]; }
    __syncthreads();
  }
  float mu = r1[0]*(1.0f/3120.0f), var = r2[0]*(1.0f/3120.0f) - mu*mu;
  float rs = rsqrtf(fmaxf(var, EPSV));
  for (int k=tid; k<3120; k+=256){
    int c = k/65, f = k - c*65;
    size_t idx = (((size_t)b*48+c)*250 + t)*65 + f;
    outb[idx] = (ysh[k]-mu)*rs*pg[k] + pbt[k] + inter[idx];
  }
}

// ---------------- fin 1x1 (48->384), 4 outputs/thread ----------------
__global__ void k_fin2(const float* __restrict__ outb, const float* __restrict__ w,
                       const float* __restrict__ bias, float* __restrict__ pi){
  int i = blockIdx.x*blockDim.x + threadIdx.x;
  if (i >= 2*96*250*65) return;
  int f = i % 65;
  int t = (i/65) % 250;
  int og = (i/(65*250)) % 96;
  int b = i/(65*250*96);
  const float* xp = outb + (size_t)b*48*250*65 + (size_t)t*65 + f;
  const float* w0 = w + og*4*48;
  float a0=bias[og*4], a1=bias[og*4+1], a2=bias[og*4+2], a3=bias[og*4+3];
  for (int c=0;c<48;c++){
    float xv = xp[(size_t)c*250*65];
    a0 += xv*w0[c]; a1 += xv*w0[48+c]; a2 += xv*w0[96+c]; a3 += xv*w0[144+c];
  }
  size_t o0 = (((size_t)b*384 + og*4)*250 + t)*65 + f;
  pi[o0] = a0; pi[o0+16250] = a1; pi[o0+2*16250] = a2; pi[o0+3*16250] = a3;
}

// ---------------- depthwise 3x3 both halves + gelu-gate ----------------
__global__ void k_dwg(const float* __restrict__ pi, const float* __restrict__ dw,
                      const float* __restrict__ db, float* __restrict__ gbuf){
  int i = blockIdx.x*blockDim.x + threadIdx.x;
  if (i >= 2*192*250*65) return;
  int f = i % 65;
  int t = (i/65) % 250;
  int j = (i/(65*250)) % 192;
  int b = i/(65*250*192);
  float x12[2];
  for (int half=0; half<2; half++){
    int ch = j + half*192;
    const float* base = pi + ((size_t)b*384 + ch)*250*65;
    const float* wr = dw + ch*9;
    float acc = db[ch];
    for (int dt=-1; dt<=1; dt++){
      int tt = t+dt;
      if (tt<0||tt>=250) continue;
      for (int df=-1; df<=1; df++){
        int ff = f+df;
        if (ff<0||ff>=65) continue;
        acc += base[(size_t)tt*65+ff]*wr[(dt+1)*3 + (df+1)];
      }
    }
    x12[half]=acc;
  }
  float x1 = x12[0];
  float g = 0.5f*x1*(1.0f+erff(x1*0.70710678118654752f));
  gbuf[i] = g * x12[1];
}

// ---------------- final 1x1 (192->48), 4 outputs/thread, + residual -> d_out ----------------
__global__ void k_final2(const float* __restrict__ gbuf, const float* __restrict__ w,
                         const float* __restrict__ bias, const float* __restrict__ outb,
                         float* __restrict__ dout){
  int i = blockIdx.x*blockDim.x + threadIdx.x;
  if (i >= 2*12*250*65) return;
  int f = i % 65;
  int t = (i/65) % 250;
  int og = (i/(65*250)) % 12;
  int b = i/(65*250*12);
  const float* gp = gbuf + (size_t)b*192*250*65 + (size_t)t*65 + f;
  const float* w0 = w + og*4*192;
  float a0=bias[og*4], a1=bias[og*4+1], a2=bias[og*4+2], a3=bias[og*4+3];
  for (int j=0;j<192;j++){
    float gv = gp[(size_t)j*250*65];
    a0 += gv*w0[j]; a1 += gv*w0[192+j]; a2 += gv*w0[384+j]; a3 += gv*w0[576+j];
  }
  size_t o0 = (((size_t)b*48 + og*4)*250 + t)*65 + f;
  dout[o0]         = a0 + outb[o0];
  dout[o0+16250]   = a1 + outb[o0+16250];
  dout[o0+2*16250] = a2 + outb[o0+2*16250];
  dout[o0+3*16250] = a3 + outb[o0+3*16250];
}

extern "C" void kernel_launch(void* const* d_in, const int* in_sizes, int n_in,
                              void* d_out, int out_size, void* d_ws, size_t ws_size,
                              hipStream_t stream) {
  (void)in_sizes; (void)n_in; (void)out_size; (void)ws_size;
  auto in = [&](int i){ return (const float*)d_in[i]; };
  const float* x        = in(0);
  const float* af_in_w  = in(1);  const float* af_in_b  = in(2);
  const float* af_out_w = in(3);  const float* af_out_b = in(4);
  const float* at_in_w  = in(5);  const float* at_in_b  = in(6);
  const float* at_out_w = in(7);  const float* at_out_b = in(8);
  const float* naf_g = in(9),  *naf_b = in(10), *nat_g = in(11), *nat_b = in(12);
  const float* intra_ng = in(13), *intra_nb = in(14), *inter_ng = in(15), *inter_nb = in(16);
  const float* intra_wif = in(17), *intra_whf = in(18), *intra_bif = in(19), *intra_bhf = in(20);
  const float* intra_wib = in(21), *intra_whb = in(22), *intra_bib = in(23), *intra_bhb = in(24);
  const float* inter_wif = in(25), *inter_whf = in(26), *inter_bif = in(27), *inter_bhf = in(28);
  const float* inter_wib = in(29), *inter_whb = in(30), *inter_bib = in(31), *inter_bhb = in(32);
  const float* il_w = in(33), *il_b = in(34), *itl_w = in(35), *itl_b = in(36);
  const float* qw = in(37), *qb = in(38), *qa = in(39), *qg = in(40), *qbt = in(41);
  const float* kw = in(42), *kb = in(43), *ka = in(44), *kg = in(45), *kbt = in(46);
  const float* vw = in(47), *vb = in(48), *va = in(49), *vg = in(50), *vbt = in(51);
  const float* pw = in(52), *pb = in(53), *pa = in(54), *pg = in(55), *pbt = in(56);
  const float* fin_w = in(57), *fin_b = in(58), *fdw_w = in(59), *fdw_b = in(60);
  const float* fout_w = in(61), *fout_b = in(62);

  float* ws = (float*)d_ws;
  float* buf_intra = ws + 0;                        // 1,560,000
  float* buf_bt    = ws + 1560000;                  // 1,560,000
  float* buf_out   = ws + 3120000;                  // 1,560,000
  unsigned int* wpk = (unsigned int*)(ws + 4680000);// 8*73728
  unsigned int* wtp = (unsigned int*)(ws + 5269824);// 2*36864
  float* scr       = ws + 5343552;                  // arena
  // staging
  float* s_seq2 = scr;                              // 1,560,000
  float* s_seq  = scr + 1560000;                    // 1,560,000
  float* s_att  = scr + 3120000;                    // 1,560,000
  // lstm buffers
  _Float16* s_pre = (_Float16*)(scr + 4680000);     // up to 49,320,960 halfs
  unsigned int* s_rT2 = (unsigned int*)(scr + 29340480); // up to 6,165,120 uints
  // phase3 aliases
  float* s_Qh = scr;                                // 1,040,000
  float* s_KT = scr + 1040000;                      // 1,040,000
  float* s_Vh = scr + 2080000;                      // 1,560,000
  float* s_Vo = scr + 3640000;                      // 1,560,000
  // phase4 aliases
  float* s_pi = scr;
  float* s_g  = scr + 12480000;

  const int thr = 256;
  auto cdiv = [](int a, int b){ return (a+b-1)/b; };

  // ---------------- weight prep (single kernel) ----------------
  k_prep<<<cdiv(663552,thr),thr,0,stream>>>(
      intra_wif, intra_whf, intra_wib, intra_whb,
      inter_wif, inter_whf, inter_wib, inter_whb,
      il_w, itl_w, wpk, wtp);

  // ---------------- Phase 1: intra (along Q): N=500, L2=62, SL=65 ----------------
  k_ln_chan<<<cdiv(2*250*65,thr), thr, 0, stream>>>(x, s_seq, intra_ng, intra_nb, 0);
  k_mha2<<<dim3(500,4), 256, 0, stream>>>(s_seq, af_in_w, af_in_b, s_att, 500, 65);
  k_projres<<<cdiv(500*65*48,thr), thr, 0, stream>>>(s_att, s_seq, af_out_w, af_out_b, s_seq2, 500*65);
  k_rowln<<<cdiv(32500,thr), thr, 0, stream>>>(s_seq2, naf_g, naf_b, 32500);
  {
    const size_t dstr = (size_t)500*62*768;
    k_pregates<<<dim3(4,500), 256, 0, stream>>>(s_seq2, wpk+0*73728, intra_bif, intra_bhf, s_pre,        62, 65);
    k_pregates<<<dim3(4,500), 256, 0, stream>>>(s_seq2, wpk+2*73728, intra_bib, intra_bhb, s_pre + dstr, 62, 65);
  }
  k_lstm12<2><<<dim3(250,2), 512, 0, stream>>>(s_pre, s_rT2, wpk+1*73728, wpk+3*73728, 500, 62);
  k_convt4<<<dim3(2,500), 256, 0, stream>>>(s_rT2, wtp+0*36864, il_b, x, buf_intra, 62, 65, 0);

  // ---------------- Phase 2: inter (along T): N=130, L2=247, SL=250 ----------------
  k_ln_chan<<<cdiv(2*250*65,thr),thr,0,stream>>>(buf_intra, s_seq, inter_ng, inter_nb, 1);
  k_mha2<<<dim3(130,4), 256, 0, stream>>>(s_seq, at_in_w, at_in_b, s_att, 130, 250);
  k_projres<<<cdiv(130*250*48,thr),thr,0,stream>>>(s_att, s_seq, at_out_w, at_out_b, s_seq2, 130*250);
  k_rowln<<<cdiv(32500,thr),thr,0,stream>>>(s_seq2, nat_g, nat_b, 32500);
  {
    const size_t dstr = (size_t)130*247*768;
    k_pregates<<<dim3(16,130), 256, 0, stream>>>(s_seq2, wpk+4*73728, inter_bif, inter_bhf, s_pre,        247, 250);
    k_pregates<<<dim3(16,130), 256, 0, stream>>>(s_seq2, wpk+6*73728, inter_bib, inter_bhb, s_pre + dstr, 247, 250);
  }
  k_lstm12<1><<<dim3(130,2), 512, 0, stream>>>(s_pre, s_rT2, wpk+5*73728, wpk+7*73728, 130, 247);
  k_convt4<<<dim3(4,130), 256, 0, stream>>>(s_rT2, wtp+1*36864, itl_b, buf_intra, buf_bt, 247, 250, 1);

  // ---------------- Phase 3: flattened-head attention ----------------
  k_hproj<<<2000,256,0,stream>>>(buf_bt, qw, qb, qa, qg, qbt, s_Qh, 8, 0);
  k_hproj<<<2000,256,0,stream>>>(buf_bt, kw, kb, ka, kg, kbt, s_KT, 8, 1);
  k_hproj<<<2000,256,0,stream>>>(buf_bt, vw, vb, va, vg, vbt, s_Vh, 12, 0);
  k_headattn2<<<dim3(25,8), 256, 0, stream>>>(s_Qh, s_KT, s_Vh, s_Vo);
  k_pprojln<<<500,256,0,stream>>>(s_Vo, pw, pb, pa, pg, pbt, buf_bt, buf_out);

  // ---------------- Phase 4: FFN ----------------
  k_fin2<<<cdiv(2*96*250*65,thr),thr,0,stream>>>(buf_out, fin_w, fin_b, s_pi);
  k_dwg<<<cdiv(2*192*250*65,thr),thr,0,stream>>>(s_pi, fdw_w, fdw_b, s_g);
  k_final2<<<cdiv(2*12*250*65,thr),thr,0,stream>>>(s_g, fout_w, fout_b, buf_out, (float*)d_out);
}

// Round 13
// 2510.685 us; speedup vs baseline: 1.3700x; 1.3237x over previous
//
#include <hip/hip_runtime.h>
#include <math.h>

#define EPSV 1e-5f

typedef _Float16 v2h __attribute__((ext_vector_type(2)));

__device__ __forceinline__ float sigf(float x){ return 1.0f/(1.0f+__expf(-x)); }
__device__ __forceinline__ float tanhf_(float x){
  float c = fminf(fmaxf(x,-10.f),10.f);
  float e = __expf(2.0f*c);
  return (e-1.0f)/(e+1.0f);
}

// LDS-only barrier: drains lgkmcnt but NOT vmcnt.
__device__ __forceinline__ void ldsbar(){
  asm volatile("s_waitcnt lgkmcnt(0)\n\ts_barrier" ::: "memory");
}

__device__ __forceinline__ float dot2u(unsigned int a, unsigned int b, float c){
#if __has_builtin(__builtin_amdgcn_fdot2)
  v2h av = __builtin_bit_cast(v2h, a);
  v2h bv = __builtin_bit_cast(v2h, b);
  return __builtin_amdgcn_fdot2(av, bv, c, false);
#else
  v2h av = __builtin_bit_cast(v2h, a);
  v2h bv = __builtin_bit_cast(v2h, b);
  return c + (float)av.x*(float)bv.x + (float)av.y*(float)bv.y;
#endif
}

// ---------------- LN over channel dim -> channel-last seq ----------------
__global__ void k_ln_chan(const float* __restrict__ src, float* __restrict__ dst,
                          const float* __restrict__ g, const float* __restrict__ bb, int mode){
  int i = blockIdx.x*blockDim.x + threadIdx.x;
  const int total = 2*250*65;
  if (i >= total) return;
  int q = i % 65; int t = (i/65) % 250; int b = i/(65*250);
  const float* p = src + (size_t)b*48*250*65 + (size_t)t*65 + q;
  float s=0.f, ss=0.f;
  for (int c=0;c<48;c++){ float v = p[(size_t)c*250*65]; s+=v; ss+=v*v; }
  float mu = s*(1.0f/48.0f);
  float var = ss*(1.0f/48.0f) - mu*mu;
  float rs = rsqrtf(fmaxf(var, EPSV));
  float* d = (mode==0) ? dst + ((size_t)(b*250+t)*65 + q)*48
                       : dst + ((size_t)(b*65+q)*250 + t)*48;
  for (int c=0;c<48;c++){ float v = p[(size_t)c*250*65]; d[c] = (v-mu)*rs*g[c] + bb[c]; }
}

// ---------------- fused qkv + MHA: block per (n,h), qkv computed in-block ----------------
__global__ __launch_bounds__(256) void k_mha2(
    const float* __restrict__ seq, const float* __restrict__ inw,
    const float* __restrict__ inb, float* __restrict__ att, int N, int L){
  __shared__ float shq[250*12];
  __shared__ float shk[250*12];
  __shared__ float shv[250*12];
  int n = blockIdx.x, h = blockIdx.y;
  for (int i = threadIdx.x; i < L*36; i += 256){
    int l = i/36, jj = i - (i/36)*36;
    int sect = jj/12, d = jj - sect*12;
    int j = sect*48 + h*12 + d;
    const float* srow = seq + ((size_t)n*L + l)*48;
    const float* wrow = inw + j*48;
    float acc = inb[j];
    for (int c=0;c<48;c++) acc += srow[c]*wrow[c];
    float* dst = (sect==0)?shq:(sect==1)?shk:shv;
    dst[l*12+d] = acc;
  }
  __syncthreads();
  const float scale = 0.28867513459481287f;
  for (int r = threadIdx.x; r < L; r += 256){
    const float4* q4 = (const float4*)(shq + r*12);
    float4 q0 = q4[0], q1 = q4[1], q2 = q4[2];
    float m = -1e30f, den = 0.0f;
    float4 o0 = make_float4(0,0,0,0), o1 = make_float4(0,0,0,0), o2 = make_float4(0,0,0,0);
    for (int j=0; j<L; j++){
      const float4* k4 = (const float4*)(shk + j*12);
      float4 k0 = k4[0], k1 = k4[1], k2 = k4[2];
      float s = q0.x*k0.x + q0.y*k0.y + q0.z*k0.z + q0.w*k0.w
              + q1.x*k1.x + q1.y*k1.y + q1.z*k1.z + q1.w*k1.w
              + q2.x*k2.x + q2.y*k2.y + q2.z*k2.z + q2.w*k2.w;
      s *= scale;
      if (s > m){
        float corr = __expf(m - s);
        den *= corr;
        o0.x*=corr; o0.y*=corr; o0.z*=corr; o0.w*=corr;
        o1.x*=corr; o1.y*=corr; o1.z*=corr; o1.w*=corr;
        o2.x*=corr; o2.y*=corr; o2.z*=corr; o2.w*=corr;
        m = s;
      }
      float e = __expf(s - m);
      den += e;
      const float4* v4 = (const float4*)(shv + j*12);
      float4 v0 = v4[0], v1 = v4[1], v2 = v4[2];
      o0.x += e*v0.x; o0.y += e*v0.y; o0.z += e*v0.z; o0.w += e*v0.w;
      o1.x += e*v1.x; o1.y += e*v1.y; o1.z += e*v1.z; o1.w += e*v1.w;
      o2.x += e*v2.x; o2.y += e*v2.y; o2.z += e*v2.z; o2.w += e*v2.w;
    }
    float inv = 1.0f/den;
    float* outp = att + ((size_t)n*L + r)*48 + h*12;
    outp[0]=o0.x*inv; outp[1]=o0.y*inv; outp[2]=o0.z*inv; outp[3]=o0.w*inv;
    outp[4]=o1.x*inv; outp[5]=o1.y*inv; outp[6]=o1.z*inv; outp[7]=o1.w*inv;
    outp[8]=o2.x*inv; outp[9]=o2.y*inv; outp[10]=o2.z*inv; outp[11]=o2.w*inv;
  }
}

// ---------------- out proj + residual ----------------
__global__ void k_projres(const float* __restrict__ att, const float* __restrict__ seq,
                          const float* __restrict__ w, const float* __restrict__ bias,
                          float* __restrict__ dst, int NL){
  int i = blockIdx.x*blockDim.x + threadIdx.x;
  if (i >= NL*48) return;
  int o = i % 48; int nl = i/48;
  const float* ar = att + (size_t)nl*48;
  const float* wr = w + o*48;
  float acc = bias[o] + seq[i];
  for (int c=0;c<48;c++) acc += ar[c]*wr[c];
  dst[i] = acc;
}

// ---------------- torch_ln over last dim (48), in place ----------------
__global__ void k_rowln(float* __restrict__ buf, const float* __restrict__ g,
                        const float* __restrict__ bb, int NL){
  int nl = blockIdx.x*blockDim.x + threadIdx.x;
  if (nl >= NL) return;
  float* p = buf + (size_t)nl*48;
  float s=0.f, ss=0.f;
  for (int c=0;c<48;c++){ float v=p[c]; s+=v; ss+=v*v; }
  float mu = s*(1.0f/48.0f);
  float var = ss*(1.0f/48.0f) - mu*mu;
  float rs = rsqrtf(var + EPSV);
  for (int c=0;c<48;c++) p[c] = (p[c]-mu)*rs*g[c] + bb[c];
}

// ---------------- fused weight prep: 8x lstm wpack + 2x convT f16-pack ----------------
__global__ void k_prep(const float* __restrict__ s0, const float* __restrict__ s1,
                       const float* __restrict__ s2, const float* __restrict__ s3,
                       const float* __restrict__ s4, const float* __restrict__ s5,
                       const float* __restrict__ s6, const float* __restrict__ s7,
                       const float* __restrict__ c0, const float* __restrict__ c1,
                       unsigned int* __restrict__ wpk, unsigned int* __restrict__ wtp){
  int i = blockIdx.x*blockDim.x + threadIdx.x;
  if (i < 589824){
    int seg = i/73728, off = i - seg*73728;
    const float* w = (seg==0)?s0:(seg==1)?s1:(seg==2)?s2:(seg==3)?s3:(seg==4)?s4:(seg==5)?s5:(seg==6)?s6:s7;
    int g = off % 768, d2 = off / 768;
    v2h v; v.x = (_Float16)w[g*192 + 2*d2]; v.y = (_Float16)w[g*192 + 2*d2 + 1];
    wpk[(size_t)seg*73728 + (size_t)d2*768 + g] = __builtin_bit_cast(unsigned int, v);
  } else if (i < 589824 + 2*36864){
    int j = i - 589824;
    int seg = j/36864, off = j - seg*36864;
    const float* w = seg ? c1 : c0;
    int c = off % 48; int ii2 = (off/48) % 192; int k = off/(48*192);
    v2h v;
    v.x = (_Float16)w[(2*ii2)*192 + c*4 + k];
    v.y = (_Float16)w[(2*ii2+1)*192 + c*4 + k];
    wtp[(size_t)seg*36864 + off] = __builtin_bit_cast(unsigned int, v);
  }
}

// ---------------- pre-gates GEMM: pre[n][l][g] = u.wi^T + bi + bh (f16 out) ----------------
__global__ __launch_bounds__(256) void k_pregates(
    const float* __restrict__ seq2, const unsigned int* __restrict__ wi,
    const float* __restrict__ bi, const float* __restrict__ bh,
    _Float16* __restrict__ pre, int L2, int SL){
  __shared__ unsigned int ut[96*16];
  int n = blockIdx.y;
  int l0 = blockIdx.x*16;
  int t = threadIdx.x;
  for (int idx=t; idx<1536; idx+=256){
    int l = idx & 15, d2 = idx >> 4;
    int li = l0 + l;
    int c = d2 >> 1, k0 = (d2 & 1)*2;
    float u0=0.f, u1=0.f;
    if (li < L2){
      const float* p = seq2 + ((size_t)n*SL + li)*48;
      u0 = p[k0*48 + c];
      u1 = p[(k0+1)*48 + c];
    }
    v2h v; v.x=(_Float16)u0; v.y=(_Float16)u1;
    ut[d2*16 + l] = __builtin_bit_cast(unsigned int, v);
  }
  __syncthreads();
  float acc[3][16];
  float b0 = bi[t] + bh[t];
  float b1 = bi[t+256] + bh[t+256];
  float b2 = bi[t+512] + bh[t+512];
  #pragma unroll
  for (int l=0;l<16;l++){ acc[0][l]=b0; acc[1][l]=b1; acc[2][l]=b2; }
  #pragma unroll 4
  for (int d2=0; d2<96; d2++){
    unsigned int w0 = wi[(size_t)d2*768 + t];
    unsigned int w1 = wi[(size_t)d2*768 + t + 256];
    unsigned int w2 = wi[(size_t)d2*768 + t + 512];
    const uint4* u4 = (const uint4*)(ut + d2*16);
    #pragma unroll
    for (int l4=0; l4<4; l4++){
      uint4 uu = u4[l4];
      acc[0][l4*4+0] = dot2u(uu.x, w0, acc[0][l4*4+0]);
      acc[0][l4*4+1] = dot2u(uu.y, w0, acc[0][l4*4+1]);
      acc[0][l4*4+2] = dot2u(uu.z, w0, acc[0][l4*4+2]);
      acc[0][l4*4+3] = dot2u(uu.w, w0, acc[0][l4*4+3]);
      acc[1][l4*4+0] = dot2u(uu.x, w1, acc[1][l4*4+0]);
      acc[1][l4*4+1] = dot2u(uu.y, w1, acc[1][l4*4+1]);
      acc[1][l4*4+2] = dot2u(uu.z, w1, acc[1][l4*4+2]);
      acc[1][l4*4+3] = dot2u(uu.w, w1, acc[1][l4*4+3]);
      acc[2][l4*4+0] = dot2u(uu.x, w2, acc[2][l4*4+0]);
      acc[2][l4*4+1] = dot2u(uu.y, w2, acc[2][l4*4+1]);
      acc[2][l4*4+2] = dot2u(uu.z, w2, acc[2][l4*4+2]);
      acc[2][l4*4+3] = dot2u(uu.w, w2, acc[2][l4*4+3]);
    }
  }
  #pragma unroll
  for (int l=0;l<16;l++){
    int li = l0 + l;
    if (li < L2){
      _Float16* pr = pre + ((size_t)n*L2 + li)*768;
      pr[t]       = (_Float16)acc[0][l];
      pr[t+256]   = (_Float16)acc[1][l];
      pr[t+512]   = (_Float16)acc[2][l];
    }
  }
}

// ---------------- biLSTM scan v6 (best known): reg wh + LDS-only barriers + prefetch ----
// rT2 layout: uint pairs rT2[(n*192 + dir*96 + ii2)*L2 + l] = (h[2*ii2], h[2*ii2+1]) f16.
template<int G>
__global__ __launch_bounds__(1024) void k_lstm6(
    const _Float16* __restrict__ pre, unsigned int* __restrict__ rT2,
    const unsigned int* __restrict__ wh_f, const unsigned int* __restrict__ wh_b,
    int N, int L2){
  __shared__ unsigned int hh2[96*G];     // [d2][s] packed h pairs
  __shared__ float gpart[4*G*768];       // [q][s][gate-row]
  _Float16* hh2h = (_Float16*)hh2;
  int t = threadIdx.x;
  int q = t >> 8, tt = t & 255;
  int dir = blockIdx.y;
  int n0 = blockIdx.x*G;
  const unsigned int* wh = dir ? wh_b : wh_f;
  unsigned int wq[24][3];
  #pragma unroll
  for (int i=0;i<24;i++){
    const unsigned int* wr = wh + (size_t)(q*24+i)*768 + tt;
    wq[i][0] = wr[0]; wq[i][1] = wr[256]; wq[i][2] = wr[512];
  }
  const _Float16* prd = pre + (size_t)dir*(size_t)N*L2*768;
  float cst = 0.f;
  int as = t/192, aj = t - as*192;
  bool actv = (t < 192*G);
  const unsigned short* pbase = (const unsigned short*)prd;
  if (actv) pbase = (const unsigned short*)(prd + ((size_t)(n0+as)*L2)*768) + aj;
  for (int idx=t; idx<96*G; idx+=1024) hh2[idx]=0u;
  __syncthreads();

  unsigned short c0=0,c1=0,c2=0,c3=0;
  {
    int l0 = dir ? (L2-1) : 0;
    if (actv){
      const unsigned short* pp = pbase + (size_t)l0*768;
      c0 = pp[0]; c1 = pp[192]; c2 = pp[384]; c3 = pp[576];
    }
  }

  for (int step=0; step<L2; step++){
    int l = dir ? (L2-1-step) : step;
    int stepn = (step+1 < L2) ? (step+1) : step;
    int ln = dir ? (L2-1-stepn) : stepn;
    unsigned short pn0=0,pn1=0,pn2=0,pn3=0;
    if (actv){
      const unsigned short* pp = pbase + (size_t)ln*768;
      pn0 = pp[0]; pn1 = pp[192]; pn2 = pp[384]; pn3 = pp[576];
    }

    float acc0[G], acc1[G], acc2[G];
    #pragma unroll
    for (int s=0;s<G;s++){ acc0[s]=0.f; acc1[s]=0.f; acc2[s]=0.f; }
    #pragma unroll
    for (int i=0;i<24;i++){
      unsigned int hhv[G];
      if (G==4){
        uint4 hv = ((const uint4*)hh2)[q*24+i];
        hhv[0]=hv.x; hhv[1]=hv.y; hhv[2]=hv.z; hhv[3]=hv.w;
      } else if (G==2){
        uint2 hv = ((const uint2*)hh2)[q*24+i];
        hhv[0]=hv.x; hhv[1]=hv.y;
      } else {
        hhv[0] = hh2[q*24+i];
      }
      unsigned int w0 = wq[i][0], w1 = wq[i][1], w2 = wq[i][2];
      #pragma unroll
      for (int s=0;s<G;s++){
        acc0[s] = dot2u(hhv[s], w0, acc0[s]);
        acc1[s] = dot2u(hhv[s], w1, acc1[s]);
        acc2[s] = dot2u(hhv[s], w2, acc2[s]);
      }
    }
    #pragma unroll
    for (int s=0;s<G;s++){
      gpart[(q*G+s)*768 + tt]       = acc0[s];
      gpart[(q*G+s)*768 + tt + 256] = acc1[s];
      gpart[(q*G+s)*768 + tt + 512] = acc2[s];
    }
    ldsbar();

    if (actv){
      float gi = (float)__builtin_bit_cast(_Float16, c0);
      float gf = (float)__builtin_bit_cast(_Float16, c1);
      float gg = (float)__builtin_bit_cast(_Float16, c2);
      float go = (float)__builtin_bit_cast(_Float16, c3);
      #pragma unroll
      for (int qq=0; qq<4; qq++){
        const float* gp = gpart + (qq*G+as)*768;
        gi += gp[aj]; gf += gp[aj+192]; gg += gp[aj+384]; go += gp[aj+576];
      }
      float ig = sigf(gi), fg = sigf(gf), g2 = tanhf_(gg), og = sigf(go);
      cst = fg*cst + ig*g2;
      float hn = og*tanhf_(cst);
      hh2h[((aj>>1)*G + as)*2 + (aj&1)] = (_Float16)hn;
    }
    ldsbar();

    if (t < 96*G){
      int s = t/96, ii2 = t - s*96;
      unsigned int v = hh2[ii2*G + s];
      rT2[((size_t)(n0+s)*192 + dir*96 + ii2)*L2 + l] = v;
    }
    c0 = pn0; c1 = pn1; c2 = pn2; c3 = pn3;
  }
}

// ---------------- conv_transpose1d v4: scalar (SMEM) weights, coalesced rT2 reads -------
__global__ __launch_bounds__(256) void k_convt4(
    const unsigned int* __restrict__ rT2, const unsigned int* __restrict__ wtp,
    const float* __restrict__ bias, const float* __restrict__ resid,
    float* __restrict__ dst, int L2, int OL, int mode){
  int n = blockIdx.y;
  int pos = blockIdx.x*64 + (threadIdx.x & 63);
  int cq = __builtin_amdgcn_readfirstlane((int)(threadIdx.x >> 6));
  float acc[12];
  #pragma unroll
  for (int c=0;c<12;c++) acc[c]=0.f;
  const unsigned int* rbase = rT2 + (size_t)n*192*L2;
  for (int k=0;k<4;k++){
    int l = pos - k;
    bool v = (l>=0) && (l<L2);
    int lc = v ? l : 0;
    const unsigned int* wk = wtp + (size_t)k*192*48 + cq*12;
    #pragma unroll 4
    for (int ii2=0; ii2<192; ii2++){
      unsigned int rp = v ? rbase[(size_t)ii2*L2 + lc] : 0u;
      const unsigned int* wrow = wk + ii2*48;
      #pragma unroll
      for (int c=0;c<12;c++) acc[c] = dot2u(rp, wrow[c], acc[c]);
    }
  }
  if (pos < OL){
    for (int c12=0;c12<12;c12++){
      int c = cq*12 + c12;
      size_t oidx;
      if (mode==0){ int b=n/250, t=n%250; oidx = (((size_t)b*48+c)*250+t)*65+pos; }
      else        { int b=n/65,  qq=n%65; oidx = (((size_t)b*48+c)*250+pos)*65+qq; }
      dst[oidx] = acc[c12] + bias[c] + resid[oidx];
    }
  }
}

// ---------------- fused head projection + leaky + ln_clamp, bt tile in LDS ----------
__global__ __launch_bounds__(256) void k_hproj(
    const float* __restrict__ bt, const float* __restrict__ w,
    const float* __restrict__ bias, const float* __restrict__ alpha,
    const float* __restrict__ g, const float* __restrict__ beta,
    float* __restrict__ dst, int dim, int kt_mode){
  __shared__ float tsh[3120];
  __shared__ float ybuf[780];
  __shared__ float r1[256];
  __shared__ float r2[256];
  int bx = blockIdx.x;          // (h*2+b)*250+t
  int h = bx/500; int rem = bx - h*500; int b = rem/250; int t = rem - b*250;
  int ny = dim*65;
  int tid = threadIdx.x;
  const float* bbase = bt + (size_t)b*48*250*65 + (size_t)t*65;
  for (int kidx=tid; kidx<3120; kidx+=256){
    int c = kidx/65, f = kidx - c*65;
    tsh[kidx] = bbase[(size_t)c*250*65 + f];
  }
  __syncthreads();
  float al = alpha[h];
  float s=0.f, ss=0.f;
  for (int kidx=tid; kidx<ny; kidx+=256){
    int e = kidx/65, f = kidx - e*65;
    const float* wr = w + (h*dim+e)*48;
    float acc = bias[h*dim+e];
    for (int c=0;c<48;c++) acc += tsh[c*65+f]*wr[c];
    if (acc < 0.f) acc *= al;
    ybuf[kidx] = acc; s += acc; ss += acc*acc;
  }
  r1[tid]=s; r2[tid]=ss; __syncthreads();
  for (int st=128; st>0; st>>=1){
    if (tid<st){ r1[tid]+=r1[tid+st]; r2[tid]+=r2[tid+st]; }
    __syncthreads();
  }
  float mu = r1[0]/(float)ny, var = r2[0]/(float)ny - mu*mu;
  float rs = rsqrtf(fmaxf(var, EPSV));
  for (int kidx=tid; kidx<ny; kidx+=256){
    float y = (ybuf[kidx]-mu)*rs*g[h*ny+kidx] + beta[h*ny+kidx];
    if (kt_mode) dst[((size_t)(h*2+b)*520 + kidx)*250 + t] = y;
    else         dst[(size_t)bx*ny + kidx] = y;
  }
}

// ---------------- flattened-head attention v2: block per (hb, 10-t tile) ----------------
__global__ __launch_bounds__(256) void k_headattn2(
    const float* __restrict__ Qp, const float* __restrict__ KT,
    const float* __restrict__ Vp, float* __restrict__ Vo){
  __shared__ float qsh[10*520];
  __shared__ float psh[10*250];
  __shared__ float rinv[10];
  int t0 = blockIdx.x*10;
  int hb = blockIdx.y;
  int h = hb >> 1, b = hb & 1;
  int tid = threadIdx.x;
  const float* qbase = Qp + ((size_t)hb*250 + t0)*520;
  for (int i=tid; i<5200; i+=256) qsh[i] = qbase[i];
  __syncthreads();
  const float scale = 0.04385290096535147f; // 1/sqrt(520)
  if (tid < 250){
    float sc[10];
    #pragma unroll
    for (int i=0;i<10;i++) sc[i]=0.f;
    const float* kcol = KT + (size_t)hb*520*250 + tid;
    for (int d=0; d<520; d++){
      float kv = kcol[(size_t)d*250];
      #pragma unroll
      for (int i=0;i<10;i++) sc[i] += qsh[i*520+d]*kv;
    }
    #pragma unroll
    for (int i=0;i<10;i++) psh[i*250+tid] = sc[i]*scale;
  }
  __syncthreads();
  if (tid < 10){
    float m = -1e30f;
    for (int s2=0;s2<250;s2++) m = fmaxf(m, psh[tid*250+s2]);
    float den = 0.f;
    for (int s2=0;s2<250;s2++){
      float e = __expf(psh[tid*250+s2]-m);
      psh[tid*250+s2]=e; den+=e;
    }
    rinv[tid] = 1.0f/den;
  }
  __syncthreads();
  float acc[10][4];
  #pragma unroll
  for (int i=0;i<10;i++)
    #pragma unroll
    for (int s=0;s<4;s++) acc[i][s]=0.f;
  for (int s2=0; s2<250; s2++){
    const float* vrow = Vp + ((size_t)hb*250 + s2)*780;
    float p[10];
    #pragma unroll
    for (int i=0;i<10;i++) p[i] = psh[i*250+s2];
    #pragma unroll
    for (int slot=0; slot<4; slot++){
      int d = tid + slot*256;
      if (d < 780){
        float v = vrow[d];
        #pragma unroll
        for (int i=0;i<10;i++) acc[i][slot] += p[i]*v;
      }
    }
  }
  #pragma unroll
  for (int slot=0; slot<4; slot++){
    int d = tid + slot*256;
    if (d < 780){
      int e = d/65, f = d - e*65;
      #pragma unroll
      for (int i=0;i<10;i++){
        Vo[(((size_t)b*48 + h*12 + e)*250 + (t0+i))*65 + f] = acc[i][slot]*rinv[i];
      }
    }
  }
}

// ---------------- fused p-projection + leaky + ln_clamp + residual ----------------
__global__ __launch_bounds__(256) void k_pprojln(
    const float* __restrict__ Vo, const float* __restrict__ pw,
    const float* __restrict__ pb, const float* __restrict__ pa,
    const float* __restrict__ pg, const float* __restrict__ pbt,
    const float* __restrict__ inter, float* __restrict__ outb){
  __shared__ float vsh[3120];
  __shared__ float ysh[3120];
  __shared__ float r1[256];
  __shared__ float r2[256];
  int bx = blockIdx.x;
  int t = bx % 250, b = bx/250;
  int tid = threadIdx.x;
  const float* vbase = Vo + (size_t)b*48*250*65 + (size_t)t*65;
  for (int k=tid; k<3120; k+=256){
    int c = k/65, f = k - c*65;
    vsh[k] = vbase[(size_t)c*250*65 + f];
  }
  __syncthreads();
  float pav = pa[0];
  float s=0.f, ss=0.f;
  for (int k=tid; k<3120; k+=256){
    int o = k/65, f = k - o*65;
    const float* wr = pw + o*48;
    float acc = pb[o];
    for (int c=0;c<48;c++) acc += vsh[c*65+f]*wr[c];
    if (acc < 0.f) acc *= pav;
    ysh[k] = acc; s += acc; ss += acc*acc;
  }
  r1[tid]=s; r2[tid]=ss; __syncthreads();
  for (int st=128; st>0; st>>=1){
    if (tid<st){ r1[tid]+=r1[tid+st]; r2[tid]+=r2[tid+st]; }
    __syncthreads();
  }
  float mu = r1[0]*(1.0f/3120.0f), var = r2[0]*(1.0f/3120.0f) - mu*mu;
  float rs = rsqrtf(fmaxf(var, EPSV));
  for (int k=tid; k<3120; k+=256){
    int c = k/65, f = k - c*65;
    size_t idx = (((size_t)b*48+c)*250 + t)*65 + f;
    outb[idx] = (ysh[k]-mu)*rs*pg[k] + pbt[k] + inter[idx];
  }
}

// ---------------- fin 1x1 (48->384), 4 outputs/thread ----------------
__global__ void k_fin2(const float* __restrict__ outb, const float* __restrict__ w,
                       const float* __restrict__ bias, float* __restrict__ pi){
  int i = blockIdx.x*blockDim.x + threadIdx.x;
  if (i >= 2*96*250*65) return;
  int f = i % 65;
  int t = (i/65) % 250;
  int og = (i/(65*250)) % 96;
  int b = i/(65*250*96);
  const float* xp = outb + (size_t)b*48*250*65 + (size_t)t*65 + f;
  const float* w0 = w + og*4*48;
  float a0=bias[og*4], a1=bias[og*4+1], a2=bias[og*4+2], a3=bias[og*4+3];
  for (int c=0;c<48;c++){
    float xv = xp[(size_t)c*250*65];
    a0 += xv*w0[c]; a1 += xv*w0[48+c]; a2 += xv*w0[96+c]; a3 += xv*w0[144+c];
  }
  size_t o0 = (((size_t)b*384 + og*4)*250 + t)*65 + f;
  pi[o0] = a0; pi[o0+16250] = a1; pi[o0+2*16250] = a2; pi[o0+3*16250] = a3;
}

// ---------------- depthwise 3x3 both halves + gelu-gate ----------------
__global__ void k_dwg(const float* __restrict__ pi, const float* __restrict__ dw,
                      const float* __restrict__ db, float* __restrict__ gbuf){
  int i = blockIdx.x*blockDim.x + threadIdx.x;
  if (i >= 2*192*250*65) return;
  int f = i % 65;
  int t = (i/65) % 250;
  int j = (i/(65*250)) % 192;
  int b = i/(65*250*192);
  float x12[2];
  for (int half=0; half<2; half++){
    int ch = j + half*192;
    const float* base = pi + ((size_t)b*384 + ch)*250*65;
    const float* wr = dw + ch*9;
    float acc = db[ch];
    for (int dt=-1; dt<=1; dt++){
      int tt = t+dt;
      if (tt<0||tt>=250) continue;
      for (int df=-1; df<=1; df++){
        int ff = f+df;
        if (ff<0||ff>=65) continue;
        acc += base[(size_t)tt*65+ff]*wr[(dt+1)*3 + (df+1)];
      }
    }
    x12[half]=acc;
  }
  float x1 = x12[0];
  float g = 0.5f*x1*(1.0f+erff(x1*0.70710678118654752f));
  gbuf[i] = g * x12[1];
}

// ---------------- final 1x1 (192->48), 4 outputs/thread, + residual -> d_out ----------------
__global__ void k_final2(const float* __restrict__ gbuf, const float* __restrict__ w,
                         const float* __restrict__ bias, const float* __restrict__ outb,
                         float* __restrict__ dout){
  int i = blockIdx.x*blockDim.x + threadIdx.x;
  if (i >= 2*12*250*65) return;
  int f = i % 65;
  int t = (i/65) % 250;
  int og = (i/(65*250)) % 12;
  int b = i/(65*250*12);
  const float* gp = gbuf + (size_t)b*192*250*65 + (size_t)t*65 + f;
  const float* w0 = w + og*4*192;
  float a0=bias[og*4], a1=bias[og*4+1], a2=bias[og*4+2], a3=bias[og*4+3];
  for (int j=0;j<192;j++){
    float gv = gp[(size_t)j*250*65];
    a0 += gv*w0[j]; a1 += gv*w0[192+j]; a2 += gv*w0[384+j]; a3 += gv*w0[576+j];
  }
  size_t o0 = (((size_t)b*48 + og*4)*250 + t)*65 + f;
  dout[o0]         = a0 + outb[o0];
  dout[o0+16250]   = a1 + outb[o0+16250];
  dout[o0+2*16250] = a2 + outb[o0+2*16250];
  dout[o0+3*16250] = a3 + outb[o0+3*16250];
}

extern "C" void kernel_launch(void* const* d_in, const int* in_sizes, int n_in,
                              void* d_out, int out_size, void* d_ws, size_t ws_size,
                              hipStream_t stream) {
  (void)in_sizes; (void)n_in; (void)out_size; (void)ws_size;
  auto in = [&](int i){ return (const float*)d_in[i]; };
  const float* x        = in(0);
  const float* af_in_w  = in(1);  const float* af_in_b  = in(2);
  const float* af_out_w = in(3);  const float* af_out_b = in(4);
  const float* at_in_w  = in(5);  const float* at_in_b  = in(6);
  const float* at_out_w = in(7);  const float* at_out_b = in(8);
  const float* naf_g = in(9),  *naf_b = in(10), *nat_g = in(11), *nat_b = in(12);
  const float* intra_ng = in(13), *intra_nb = in(14), *inter_ng = in(15), *inter_nb = in(16);
  const float* intra_wif = in(17), *intra_whf = in(18), *intra_bif = in(19), *intra_bhf = in(20);
  const float* intra_wib = in(21), *intra_whb = in(22), *intra_bib = in(23), *intra_bhb = in(24);
  const float* inter_wif = in(25), *inter_whf = in(26), *inter_bif = in(27), *inter_bhf = in(28);
  const float* inter_wib = in(29), *inter_whb = in(30), *inter_bib = in(31), *inter_bhb = in(32);
  const float* il_w = in(33), *il_b = in(34), *itl_w = in(35), *itl_b = in(36);
  const float* qw = in(37), *qb = in(38), *qa = in(39), *qg = in(40), *qbt = in(41);
  const float* kw = in(42), *kb = in(43), *ka = in(44), *kg = in(45), *kbt = in(46);
  const float* vw = in(47), *vb = in(48), *va = in(49), *vg = in(50), *vbt = in(51);
  const float* pw = in(52), *pb = in(53), *pa = in(54), *pg = in(55), *pbt = in(56);
  const float* fin_w = in(57), *fin_b = in(58), *fdw_w = in(59), *fdw_b = in(60);
  const float* fout_w = in(61), *fout_b = in(62);

  float* ws = (float*)d_ws;
  float* buf_intra = ws + 0;                        // 1,560,000
  float* buf_bt    = ws + 1560000;                  // 1,560,000
  float* buf_out   = ws + 3120000;                  // 1,560,000
  unsigned int* wpk = (unsigned int*)(ws + 4680000);// 8*73728
  unsigned int* wtp = (unsigned int*)(ws + 5269824);// 2*36864
  float* scr       = ws + 5343552;                  // arena
  // staging
  float* s_seq2 = scr;                              // 1,560,000
  float* s_seq  = scr + 1560000;                    // 1,560,000
  float* s_att  = scr + 3120000;                    // 1,560,000
  // lstm buffers
  _Float16* s_pre = (_Float16*)(scr + 4680000);     // up to 49,320,960 halfs
  unsigned int* s_rT2 = (unsigned int*)(scr + 29340480); // up to 6,165,120 uints
  // phase3 aliases
  float* s_Qh = scr;                                // 1,040,000
  float* s_KT = scr + 1040000;                      // 1,040,000
  float* s_Vh = scr + 2080000;                      // 1,560,000
  float* s_Vo = scr + 3640000;                      // 1,560,000
  // phase4 aliases
  float* s_pi = scr;
  float* s_g  = scr + 12480000;

  const int thr = 256;
  auto cdiv = [](int a, int b){ return (a+b-1)/b; };

  // ---------------- weight prep (single kernel) ----------------
  k_prep<<<cdiv(663552,thr),thr,0,stream>>>(
      intra_wif, intra_whf, intra_wib, intra_whb,
      inter_wif, inter_whf, inter_wib, inter_whb,
      il_w, itl_w, wpk, wtp);

  // ---------------- Phase 1: intra (along Q): N=500, L2=62, SL=65 ----------------
  k_ln_chan<<<cdiv(2*250*65,thr), thr, 0, stream>>>(x, s_seq, intra_ng, intra_nb, 0);
  k_mha2<<<dim3(500,4), 256, 0, stream>>>(s_seq, af_in_w, af_in_b, s_att, 500, 65);
  k_projres<<<cdiv(500*65*48,thr), thr, 0, stream>>>(s_att, s_seq, af_out_w, af_out_b, s_seq2, 500*65);
  k_rowln<<<cdiv(32500,thr), thr, 0, stream>>>(s_seq2, naf_g, naf_b, 32500);
  {
    const size_t dstr = (size_t)500*62*768;
    k_pregates<<<dim3(4,500), 256, 0, stream>>>(s_seq2, wpk+0*73728, intra_bif, intra_bhf, s_pre,        62, 65);
    k_pregates<<<dim3(4,500), 256, 0, stream>>>(s_seq2, wpk+2*73728, intra_bib, intra_bhb, s_pre + dstr, 62, 65);
  }
  k_lstm6<4><<<dim3(125,2), 1024, 0, stream>>>(s_pre, s_rT2, wpk+1*73728, wpk+3*73728, 500, 62);
  k_convt4<<<dim3(2,500), 256, 0, stream>>>(s_rT2, wtp+0*36864, il_b, x, buf_intra, 62, 65, 0);

  // ---------------- Phase 2: inter (along T): N=130, L2=247, SL=250 ----------------
  k_ln_chan<<<cdiv(2*250*65,thr),thr,0,stream>>>(buf_intra, s_seq, inter_ng, inter_nb, 1);
  k_mha2<<<dim3(130,4), 256, 0, stream>>>(s_seq, at_in_w, at_in_b, s_att, 130, 250);
  k_projres<<<cdiv(130*250*48,thr),thr,0,stream>>>(s_att, s_seq, at_out_w, at_out_b, s_seq2, 130*250);
  k_rowln<<<cdiv(32500,thr),thr,0,stream>>>(s_seq2, nat_g, nat_b, 32500);
  {
    const size_t dstr = (size_t)130*247*768;
    k_pregates<<<dim3(16,130), 256, 0, stream>>>(s_seq2, wpk+4*73728, inter_bif, inter_bhf, s_pre,        247, 250);
    k_pregates<<<dim3(16,130), 256, 0, stream>>>(s_seq2, wpk+6*73728, inter_bib, inter_bhb, s_pre + dstr, 247, 250);
  }
  k_lstm6<1><<<dim3(130,2), 1024, 0, stream>>>(s_pre, s_rT2, wpk+5*73728, wpk+7*73728, 130, 247);
  k_convt4<<<dim3(4,130), 256, 0, stream>>>(s_rT2, wtp+1*36864, itl_b, buf_intra, buf_bt, 247, 250, 1);

  // ---------------- Phase 3: flattened-head attention ----------------
  k_hproj<<<2000,256,0,stream>>>(buf_bt, qw, qb, qa, qg, qbt, s_Qh, 8, 0);
  k_hproj<<<2000,256,0,stream>>>(buf_bt, kw, kb, ka, kg, kbt, s_KT, 8, 1);
  k_hproj<<<2000,256,0,stream>>>(buf_bt, vw, vb, va, vg, vbt, s_Vh, 12, 0);
  k_headattn2<<<dim3(25,8), 256, 0, stream>>>(s_Qh, s_KT, s_Vh, s_Vo);
  k_pprojln<<<500,256,0,stream>>>(s_Vo, pw, pb, pa, pg, pbt, buf_bt, buf_out);

  // ---------------- Phase 4: FFN ----------------
  k_fin2<<<cdiv(2*96*250*65,thr),thr,0,stream>>>(buf_out, fin_w, fin_b, s_pi);
  k_dwg<<<cdiv(2*192*250*65,thr),thr,0,stream>>>(s_pi, fdw_w, fdw_b, s_g);
  k_final2<<<cdiv(2*12*250*65,thr),thr,0,stream>>>(s_g, fout_w, fout_b, buf_out, (float*)d_out);
}